// Round 16
// baseline (518.483 us; speedup 1.0000x reference)
//
#include <hip/hip_runtime.h>
#include <math.h>

// Problem constants: B=4, N=256, D=512, H=8, HD=64, L=3, K_SPARSE=25, EPS=1e-5

typedef __attribute__((ext_vector_type(8))) short bf16x8;
typedef __attribute__((ext_vector_type(4))) float f32x4;
typedef __attribute__((ext_vector_type(8))) unsigned short ushort8v;

__device__ __forceinline__ unsigned short f2bf(float x) {
    union { float f; unsigned int u; } c; c.f = x;
    unsigned int r = (c.u + 0x7fffu + ((c.u >> 16) & 1u)) >> 16;
    return (unsigned short)r;
}

// ---------------------------------------------------------------------------
// GEMM device body (f32): C[M,N] = act(A[M,K] @ W[K,N] + bias).
// TM=64: 4 rows x 4 cols/thread; TM=32: 2 rows x 4 cols.
// flags: 1 = relu, 2 = pool. wmode: 0 none; 2 = we1-split.
// ---------------------------------------------------------------------------
template <int TM>
__device__ __forceinline__ void gemm_dev(
    char* smem, const float* __restrict__ A, const float* __restrict__ W,
    const float* __restrict__ bias, float* __restrict__ C,
    int M, int N, int K, int flags, int wmode, int bx, int by)
{
    constexpr int RT = TM / 16;
    float (*As)[TM + 4] = (float (*)[TM + 4])smem;
    float (*Ws)[68] = (float (*)[68])(smem + 16 * (TM + 4) * sizeof(float));

    const int tid = threadIdx.x;
    const int tx = tid & 15, ty = tid >> 4;
    const int bm = by * TM, bn = bx * 64;

    const float* Wp = W;
    const float* bp = bias;
    int wn = N, wcol = bn;
    if (wmode == 2) {
        if (bn >= 512) Wp += 262144; else bp = nullptr;
        wn = 512; wcol = bn & 511;
    }

    constexpr int AV = (TM == 64) ? 4 : 2;
    const int ar = (TM == 64) ? (tid >> 2) : (tid >> 3);
    const int ac = (TM == 64) ? ((tid & 3) << 2) : ((tid & 7) << 1);
    const int wr = tid >> 4;
    const int wc = (tid & 15) << 2;

    const float* Aptr = A + (size_t)(bm + ar) * K + ac;
    const float* Wptr = Wp + (size_t)wr * wn + wcol + wc;

    float acc[RT][4] = {};
    float ra[AV], rw[4];

#define LOADREGS(k0_) do {                                                   \
        const float* ap_ = Aptr + (k0_);                                     \
        if constexpr (TM == 64) {                                            \
            float4 v_ = *(const float4*)ap_;                                 \
            ra[0]=v_.x; ra[1]=v_.y; ra[2]=v_.z; ra[3]=v_.w;                  \
        } else {                                                             \
            float2 v_ = *(const float2*)ap_; ra[0]=v_.x; ra[1]=v_.y;         \
        }                                                                    \
        float4 w_ = *(const float4*)(Wptr + (size_t)(k0_) * wn);             \
        rw[0]=w_.x; rw[1]=w_.y; rw[2]=w_.z; rw[3]=w_.w; } while (0)

    LOADREGS(0);

    for (int k0 = 0; k0 < K; k0 += 16) {
        if (k0) __syncthreads();
        #pragma unroll
        for (int u = 0; u < AV; ++u) As[ac + u][ar] = ra[u];
        #pragma unroll
        for (int u = 0; u < 4; ++u) Ws[wr][wc + u] = rw[u];
        __syncthreads();

        if (k0 + 16 < K) LOADREGS(k0 + 16);

        #pragma unroll
        for (int kk = 0; kk < 16; ++kk) {
            float a[RT];
            if constexpr (RT == 4) {
                float4 t = *(const float4*)&As[kk][ty * 4];
                a[0]=t.x; a[1]=t.y; a[2]=t.z; a[3]=t.w;
            } else {
                float2 t = *(const float2*)&As[kk][ty * 2];
                a[0]=t.x; a[1]=t.y;
            }
            float4 tw = *(const float4*)&Ws[kk][tx * 4];
            float w[4] = {tw.x, tw.y, tw.z, tw.w};
            #pragma unroll
            for (int i = 0; i < RT; ++i)
                #pragma unroll
                for (int j = 0; j < 4; ++j)
                    acc[i][j] = fmaf(a[i], w[j], acc[i][j]);
        }
    }
#undef LOADREGS

    #pragma unroll
    for (int j = 0; j < 4; ++j) {
        const int cn = bn + tx * 4 + j;
        const float bv = bp ? bp[wcol + tx * 4 + j] : 0.f;
        if (flags & 2) {
            #pragma unroll
            for (int pi = 0; pi < RT / 2; ++pi) {
                float f0 = acc[2 * pi][j] + bv;
                float f1 = acc[2 * pi + 1][j] + bv;
                if (flags & 1) { f0 = fmaxf(f0, 0.f); f1 = fmaxf(f1, 0.f); }
                int prow = ((bm + ty * RT) >> 1) + pi;
                C[(size_t)prow * N + cn] = (f0 + f1) * 0.5f;
            }
        } else {
            #pragma unroll
            for (int i = 0; i < RT; ++i) {
                float f = acc[i][j] + bv;
                if (flags & 1) f = fmaxf(f, 0.f);
                C[(size_t)(bm + ty * RT + i) * N + cn] = f;
            }
        }
    }
}

template <int TM>
__global__ __launch_bounds__(256) void gemm_v6(
    const float* __restrict__ A, const float* __restrict__ W,
    const float* __restrict__ bias, float* __restrict__ C,
    int M, int N, int K, int flags, int wmode)
{
    constexpr int SB = (TM == 64) ? 8704 : 6656;
    __shared__ __align__(16) char smem[SB];
    gemm_dev<TM>(smem, A, W, bias, C, M, N, K, flags, wmode, blockIdx.x, blockIdx.y);
}

// ---------------------------------------------------------------------------
// Transpose + f32->bf16 device body: Wt[N][K] = W[K][N]. 64x64 tiles.
// ---------------------------------------------------------------------------
__device__ __forceinline__ void cvt_dev(
    char* smem, const float* __restrict__ W, unsigned short* __restrict__ Wt,
    int K, int N, int bx, int by)
{
    unsigned short (*t)[72] = (unsigned short (*)[72])smem;
    const int n0 = bx * 64, k0 = by * 64;
    const int tid = threadIdx.x;
    const int rr = tid >> 4, c4 = (tid & 15) << 2;
    #pragma unroll
    for (int u = 0; u < 4; ++u) {
        const float4 v = *(const float4*)(W + (size_t)(k0 + rr + u * 16) * N + n0 + c4);
        t[c4 + 0][rr + u * 16] = f2bf(v.x);
        t[c4 + 1][rr + u * 16] = f2bf(v.y);
        t[c4 + 2][rr + u * 16] = f2bf(v.z);
        t[c4 + 3][rr + u * 16] = f2bf(v.w);
    }
    __syncthreads();
    const int orow = tid >> 2, oc = (tid & 3) << 4;
    unsigned short* dst = Wt + (size_t)(n0 + orow) * K + k0 + oc;
    *(ushort8v*)(dst + 0) = *(const ushort8v*)&t[orow][oc + 0];
    *(ushort8v*)(dst + 8) = *(const ushort8v*)&t[orow][oc + 8];
}

// ---------------------------------------------------------------------------
// MFMA bf16 GEMM device body (no LDS): C = A(bf16) @ Bt^T + bias.
// Block 256 = 4 waves; wave tile 32x64; block tile 128x64.
// ---------------------------------------------------------------------------
__device__ __forceinline__ void mfma_dev(
    const unsigned short* __restrict__ Ab, const unsigned short* __restrict__ Bt,
    const float* __restrict__ bias, float* __restrict__ C,
    int M, int N, int K, int ldc, int bx, int by)
{
    const int lane = threadIdx.x & 63;
    const int wv = threadIdx.x >> 6;
    const int bn = bx * 64;
    const int bm = by * 128 + wv * 32;
    const int l15 = lane & 15;
    const int kb = (lane >> 4) * 8;

    const unsigned short* a0p = Ab + (size_t)(bm + l15) * K + kb;
    const unsigned short* a1p = a0p + (size_t)16 * K;
    const unsigned short* bp0 = Bt + (size_t)(bn + l15) * K + kb;

    f32x4 acc[2][4];
    #pragma unroll
    for (int i = 0; i < 2; ++i)
        #pragma unroll
        for (int j = 0; j < 4; ++j)
            acc[i][j] = (f32x4){0.f, 0.f, 0.f, 0.f};

    for (int k0 = 0; k0 < K; k0 += 32) {
        const bf16x8 a0 = *(const bf16x8*)(a0p + k0);
        const bf16x8 a1 = *(const bf16x8*)(a1p + k0);
        #pragma unroll
        for (int nf = 0; nf < 4; ++nf) {
            const bf16x8 b = *(const bf16x8*)(bp0 + (size_t)nf * 16 * K + k0);
            acc[0][nf] = __builtin_amdgcn_mfma_f32_16x16x32_bf16(a0, b, acc[0][nf], 0, 0, 0);
            acc[1][nf] = __builtin_amdgcn_mfma_f32_16x16x32_bf16(a1, b, acc[1][nf], 0, 0, 0);
        }
    }

    const int r0 = (lane >> 4) * 4;
    #pragma unroll
    for (int mf = 0; mf < 2; ++mf)
        #pragma unroll
        for (int nf = 0; nf < 4; ++nf) {
            const int col = bn + nf * 16 + l15;
            const float bv = bias ? bias[col] : 0.f;
            #pragma unroll
            for (int r = 0; r < 4; ++r) {
                const int row = bm + mf * 16 + r0 + r;
                C[(size_t)row * ldc + col] = acc[mf][nf][r] + bv;
            }
        }
}

// ---------------------------------------------------------------------------
// Fused MHA device body v4. Block = (16 q-rows, h, b), 4 waves; wave owns 4
// q-rows. NT = n/64. Q read via wave-uniform GLOBAL loads (scalar path, no
// LDS) - values and FMA order identical to v3 (bit-identical outputs).
// K/V staged in LDS (V transposed). out (f32) / outb (bf16) both optional.
// LDS: kv[64][68] @0 (17408) + p[16][256] @17408 (16384) = 33792 B.
// ---------------------------------------------------------------------------
template <int NT>
__device__ __forceinline__ void attn_dev(
    char* smem, const float* __restrict__ qkv, float* __restrict__ out,
    unsigned short* __restrict__ outb, int n, int qstride,
    int bx, int by, int bz)
{
    float (*kv_lds)[68] = (float (*)[68])smem;
    float (*p_lds)[256] = (float (*)[256])(smem + 17408);

    const int lane = threadIdx.x & 63;
    const int w    = threadIdx.x >> 6;
    const int h = by, b = bz;
    const int q0 = bx * 16;
    const size_t base = (size_t)b * n * qstride;

    const int r0 = w * 4;
    const int sr = threadIdx.x >> 2;
    const int sq = threadIdx.x & 3;

    // wave-uniform Q row pointers (scalar-load path)
    const float* qp = qkv + base + (size_t)(q0 + r0) * qstride + h * 64;
    const float* qp1 = qp + qstride;
    const float* qp2 = qp + 2 * qstride;
    const float* qp3 = qp + 3 * qstride;

    float s[4][NT];

    // ---- QK^T ----
    #pragma unroll
    for (int t = 0; t < NT; ++t) {
        const int j0 = t * 64;
        __syncthreads();
        {   // stage K tile rows j0..j0+63 (row-major)
            const float* src = qkv + base + (size_t)(j0 + sr) * qstride + 512 + h * 64;
            #pragma unroll
            for (int u = 0; u < 4; ++u) {
                int c = u * 4 + sq;
                float4 v = *(const float4*)(src + c * 4);
                *(float4*)&kv_lds[sr][c * 4] = v;
            }
        }
        __syncthreads();
        float c0 = 0.f, c1 = 0.f, c2 = 0.f, c3 = 0.f;
        #pragma unroll
        for (int d = 0; d < 64; d += 4) {
            const float4 kv = *(const float4*)&kv_lds[lane][d];
            const float4 qa = *(const float4*)(qp + d);    // wave-uniform
            const float4 qb = *(const float4*)(qp1 + d);
            const float4 qc = *(const float4*)(qp2 + d);
            const float4 qd = *(const float4*)(qp3 + d);
            c0 = fmaf(qa.x, kv.x, c0); c0 = fmaf(qa.y, kv.y, c0);
            c0 = fmaf(qa.z, kv.z, c0); c0 = fmaf(qa.w, kv.w, c0);
            c1 = fmaf(qb.x, kv.x, c1); c1 = fmaf(qb.y, kv.y, c1);
            c1 = fmaf(qb.z, kv.z, c1); c1 = fmaf(qb.w, kv.w, c1);
            c2 = fmaf(qc.x, kv.x, c2); c2 = fmaf(qc.y, kv.y, c2);
            c2 = fmaf(qc.z, kv.z, c2); c2 = fmaf(qc.w, kv.w, c2);
            c3 = fmaf(qd.x, kv.x, c3); c3 = fmaf(qd.y, kv.y, c3);
            c3 = fmaf(qd.z, kv.z, c3); c3 = fmaf(qd.w, kv.w, c3);
        }
        s[0][t] = c0 * 0.125f; s[1][t] = c1 * 0.125f;
        s[2][t] = c2 * 0.125f; s[3][t] = c3 * 0.125f;
    }

    // ---- softmax per row ----
    double inv[4];
    #pragma unroll
    for (int qr = 0; qr < 4; ++qr) {
        float m = s[qr][0];
        #pragma unroll
        for (int t = 1; t < NT; ++t) m = fmaxf(m, s[qr][t]);
        #pragma unroll
        for (int off = 32; off; off >>= 1) m = fmaxf(m, __shfl_xor(m, off));
        double sum = 0.0;
        #pragma unroll
        for (int t = 0; t < NT; ++t) {
            float p = expf(s[qr][t] - m);
            p_lds[r0 + qr][t * 64 + lane] = p;
            sum += (double)p;
        }
        #pragma unroll
        for (int off = 32; off; off >>= 1) sum += __shfl_xor(sum, off);
        inv[qr] = 1.0 / sum;
    }

    // ---- PV (d = lane); V staged transposed vt[d][j] ----
    float o0 = 0.f, o1 = 0.f, o2 = 0.f, o3 = 0.f;
    #pragma unroll
    for (int t = 0; t < NT; ++t) {
        const int j0 = t * 64;
        __syncthreads();
        {
            const float* src = qkv + base + (size_t)(j0 + sr) * qstride + 1024 + h * 64;
            #pragma unroll
            for (int u = 0; u < 4; ++u) {
                int c = u * 4 + sq;
                float4 v = *(const float4*)(src + c * 4);
                kv_lds[c * 4 + 0][sr] = v.x;
                kv_lds[c * 4 + 1][sr] = v.y;
                kv_lds[c * 4 + 2][sr] = v.z;
                kv_lds[c * 4 + 3][sr] = v.w;
            }
        }
        __syncthreads();
        #pragma unroll
        for (int jl = 0; jl < 64; jl += 4) {
            const float4 vv = *(const float4*)&kv_lds[lane][jl];
            const float4 pa = *(const float4*)&p_lds[r0 + 0][t * 64 + jl];
            const float4 pb = *(const float4*)&p_lds[r0 + 1][t * 64 + jl];
            const float4 pc = *(const float4*)&p_lds[r0 + 2][t * 64 + jl];
            const float4 pd = *(const float4*)&p_lds[r0 + 3][t * 64 + jl];
            o0 = fmaf(pa.x, vv.x, o0); o0 = fmaf(pa.y, vv.y, o0);
            o0 = fmaf(pa.z, vv.z, o0); o0 = fmaf(pa.w, vv.w, o0);
            o1 = fmaf(pb.x, vv.x, o1); o1 = fmaf(pb.y, vv.y, o1);
            o1 = fmaf(pb.z, vv.z, o1); o1 = fmaf(pb.w, vv.w, o1);
            o2 = fmaf(pc.x, vv.x, o2); o2 = fmaf(pc.y, vv.y, o2);
            o2 = fmaf(pc.z, vv.z, o2); o2 = fmaf(pc.w, vv.w, o2);
            o3 = fmaf(pd.x, vv.x, o3); o3 = fmaf(pd.y, vv.y, o3);
            o3 = fmaf(pd.z, vv.z, o3); o3 = fmaf(pd.w, vv.w, o3);
        }
    }
    const size_t obase = ((size_t)(b * n + q0 + r0)) * 512 + h * 64 + lane;
    const float r0v = (float)((double)o0 * inv[0]);
    const float r1v = (float)((double)o1 * inv[1]);
    const float r2v = (float)((double)o2 * inv[2]);
    const float r3v = (float)((double)o3 * inv[3]);
    if (out) {
        out[obase + 0 * 512] = r0v;
        out[obase + 1 * 512] = r1v;
        out[obase + 2 * 512] = r2v;
        out[obase + 3 * 512] = r3v;
    }
    if (outb) {
        outb[obase + 0 * 512] = f2bf(r0v);
        outb[obase + 1 * 512] = f2bf(r1v);
        outb[obase + 2 * 512] = f2bf(r2v);
        outb[obase + 3 * 512] = f2bf(r3v);
    }
}

template <int NT>
__global__ __launch_bounds__(256) void attn_v3(
    const float* __restrict__ qkv, float* __restrict__ out,
    unsigned short* __restrict__ outb, int n, int qstride)
{
    __shared__ __align__(16) char smem[33792];
    attn_dev<NT>(smem, qkv, out, outb, n, qstride, blockIdx.x, blockIdx.y, blockIdx.z);
}

// ---------------------------------------------------------------------------
// Edge scores device body v5: z[i,j] = sum_d relu(hi[i,d]+hj[j,d])*w2[d].
// f32 accumulation within each 128-deep chunk, f64 across chunks (noise
// ~2e-6, same order as validated f32 hi/hj noise). We2 scalar f32 loads.
// ---------------------------------------------------------------------------
__device__ __forceinline__ void scores_dev(
    char* smem, const float* __restrict__ hq, int stride, int off,
    const float* __restrict__ We2, const float* __restrict__ be2,
    float* __restrict__ S, int bx, int by, int bz)
{
    float (*Hi)[34] = (float (*)[34])smem;             // 17408 B
    float (*Hj)[34] = (float (*)[34])(smem + 17408);   // 17408 B
    const int b = bz;
    const int i0 = by * 32, j0 = bx * 32;
    const int tid = threadIdx.x;
    const int tx = tid & 15, ty = tid >> 4;

    const int si = tid >> 3;
    const int sd = (tid & 7) << 2;

    const float* hip = hq + (size_t)(b * 256 + i0 + si) * stride + off + sd;
    const float* hjp = hq + (size_t)(b * 256 + j0 + si) * stride + off + 512 + sd;

    double a00 = 0.0, a01 = 0.0, a10 = 0.0, a11 = 0.0;

    for (int k0 = 0; k0 < 512; k0 += 128) {
        __syncthreads();
        #pragma unroll
        for (int u = 0; u < 4; ++u) {
            const int dch = u * 32 + sd;
            float4 v = *(const float4*)(hip + k0 + u * 32);
            Hi[dch + 0][si] = v.x; Hi[dch + 1][si] = v.y;
            Hi[dch + 2][si] = v.z; Hi[dch + 3][si] = v.w;
            float4 w = *(const float4*)(hjp + k0 + u * 32);
            Hj[dch + 0][si] = w.x; Hj[dch + 1][si] = w.y;
            Hj[dch + 2][si] = w.z; Hj[dch + 3][si] = w.w;
        }
        __syncthreads();
        float c00 = 0.f, c01 = 0.f, c10 = 0.f, c11 = 0.f;
        #pragma unroll 16
        for (int kk = 0; kk < 128; ++kk) {
            const float wv = We2[k0 + kk];   // wave-uniform -> s_load
            const float2 hi = *(const float2*)&Hi[kk][ty * 2];
            const float2 hj = *(const float2*)&Hj[kk][tx * 2];
            c00 = fmaf(fmaxf(hi.x + hj.x, 0.f), wv, c00);
            c01 = fmaf(fmaxf(hi.x + hj.y, 0.f), wv, c01);
            c10 = fmaf(fmaxf(hi.y + hj.x, 0.f), wv, c10);
            c11 = fmaf(fmaxf(hi.y + hj.y, 0.f), wv, c11);
        }
        a00 += (double)c00; a01 += (double)c01;
        a10 += (double)c10; a11 += (double)c11;
    }

    const double bb = (double)be2[0];
    const int gi0 = i0 + ty * 2, gj0 = j0 + tx * 2;
    double zz[2][2] = {{a00, a01}, {a10, a11}};
    #pragma unroll
    for (int ii = 0; ii < 2; ++ii)
        #pragma unroll
        for (int jj = 0; jj < 2; ++jj) {
            double z = zz[ii][jj] + bb;
            float sc_ = (float)(1.0 / (1.0 + exp(-z)));
            if (gi0 + ii == gj0 + jj) sc_ = 0.f;
            S[(size_t)(b * 256 + gi0 + ii) * 256 + gj0 + jj] = sc_;
        }
}

// ---------------------------------------------------------------------------
// Top-k(25) one-hot per row of 256, one WAVE per row (ties -> lower index).
// ---------------------------------------------------------------------------
__device__ __forceinline__ void topk_wave(
    const float* __restrict__ S, float* __restrict__ out, int row)
{
    const int lane = threadIdx.x & 63;
    float v[4]; int sel[4] = {0, 0, 0, 0};
    #pragma unroll
    for (int t = 0; t < 4; ++t) v[t] = S[(size_t)row * 256 + t * 64 + lane];
    for (int it = 0; it < 25; ++it) {
        float bv = v[0]; int bi = lane;
        #pragma unroll
        for (int t = 1; t < 4; ++t) {
            int idx = t * 64 + lane;
            if (v[t] > bv) { bv = v[t]; bi = idx; }
        }
        #pragma unroll
        for (int off = 32; off; off >>= 1) {
            float ov = __shfl_xor(bv, off);
            int   oi = __shfl_xor(bi, off);
            if (ov > bv || (ov == bv && oi < bi)) { bv = ov; bi = oi; }
        }
        if ((bi & 63) == lane) { int t = bi >> 6; sel[t] = 1; v[t] = -INFINITY; }
    }
    #pragma unroll
    for (int t = 0; t < 4; ++t)
        out[(size_t)row * 256 + t * 64 + lane] = (float)sel[t];
}

// ---------------------------------------------------------------------------
// Fused 3-way add + bias + relu + LayerNorm, one WAVE per row (4 rows/block).
// ---------------------------------------------------------------------------
__global__ __launch_bounds__(256) void ln3_k(
    const float* __restrict__ y, const float* __restrict__ bf,
    const float* __restrict__ g, const float* __restrict__ bta,
    float* __restrict__ out, unsigned short* __restrict__ outb)
{
    const int r = blockIdx.x * 4 + (threadIdx.x >> 6);
    const int lane = threadIdx.x & 63;
    const int b = r >> 8, i = r & 255;
    const float* y0 = y + (size_t)r * 512;
    const float* y1 = y + (size_t)(1024 + b * 128 + (i >> 1)) * 512;
    const float* y2 = y + (size_t)(1536 + b * 64 + (i >> 2)) * 512;
    double v[8];
    double sum = 0.0;
    #pragma unroll
    for (int t = 0; t < 8; ++t) {
        int d = t * 64 + lane;
        double s = (double)y0[d] + (double)y1[d] + (double)y2[d] + (double)bf[d];
        s = s > 0.0 ? s : 0.0;
        v[t] = s; sum += s;
    }
    #pragma unroll
    for (int off = 32; off; off >>= 1) sum += __shfl_xor(sum, off);
    const double mean = sum * (1.0 / 512.0);
    double ss = 0.0;
    #pragma unroll
    for (int t = 0; t < 8; ++t) { double d = v[t] - mean; ss += d * d; }
    #pragma unroll
    for (int off = 32; off; off >>= 1) ss += __shfl_xor(ss, off);
    const double rstd = 1.0 / sqrt(ss * (1.0 / 512.0) + 1e-5);
    #pragma unroll
    for (int t = 0; t < 8; ++t) {
        int d = t * 64 + lane;
        float f = (float)((v[t] - mean) * rstd * (double)g[d] + (double)bta[d]);
        out[(size_t)r * 512 + d] = f;
        outb[(size_t)r * 512 + d] = f2bf(f);
    }
}

// ---------------------------------------------------------------------------
// Packed dispatches (block-range union of mutually independent ops)
// ---------------------------------------------------------------------------
__global__ __launch_bounds__(256) void pack_qkv_cvt(
    const float* x, const float* Wqkv, const float* bqkv, float* qkvb,
    const float* Wsqkv, unsigned short* wqkvT,
    const float* Wso, unsigned short* wsoT)
{
    __shared__ __align__(16) char smem[9216];
    const int bid = blockIdx.x;
    if (bid < 384) {                       // qkv l0: grid (24,16)
        gemm_dev<64>(smem, x, Wqkv, bqkv, qkvb, 1024, 1536, 512, 0, 0,
                     bid % 24, bid / 24);
    } else if (bid < 576) {                // cvt Ws_qkv: grid (24,8)
        const int r = bid - 384;
        cvt_dev(smem, Wsqkv, wqkvT, 512, 1536, r % 24, r / 24);
    } else {                               // cvt Ws_o: grid (8,8)
        const int r = bid - 576;
        cvt_dev(smem, Wso, wsoT, 512, 512, r % 8, r / 8);
    }
}

// Wp1 (relu+pool) || fuse segment. nb_w = Wp1 blocks; fuse grid (8, Mf/64).
__global__ __launch_bounds__(256) void pack_wp1_fuse(
    const float* lvl, const float* Wp1, const float* bp1, float* poolb,
    const float* Wfseg, float* ydst, int Mw, int Mf, int nb_w)
{
    __shared__ __align__(16) char smem[8704];
    const int bid = blockIdx.x;
    if (bid < nb_w) {
        gemm_dev<32>(smem, lvl, Wp1, bp1, poolb, Mw, 256, 512, 3, 0,
                     bid % 4, bid / 4);
    } else {
        const int r = bid - nb_w;
        gemm_dev<64>(smem, lvl, Wfseg, nullptr, ydst, Mf, 512, 512, 0, 0,
                     r % 8, r / 8);
    }
}

__global__ __launch_bounds__(256) void pack_we1_mfma(
    const float* hier, const float* We1, const float* be1, float* hibjb,
    const unsigned short* hier_b, const unsigned short* wqkvT,
    const float* bs_qkv, float* qkvb)
{
    __shared__ __align__(16) char smem[8704];
    const int bid = blockIdx.x;
    if (bid < 256) {                       // We1: grid (16,16), wmode 2
        gemm_dev<64>(smem, hier, We1, be1, hibjb, 1024, 1024, 512, 0, 2,
                     bid % 16, bid / 16);
    } else {                               // mfma qkv: grid (24,8)
        const int r = bid - 256;
        mfma_dev(hier_b, wqkvT, bs_qkv, qkvb, 1024, 1536, 512, 1536,
                 r % 24, r / 24);
    }
}

__global__ __launch_bounds__(256) void pack_attnF_scores(
    const float* qkvb, unsigned short* attnb_b,
    const float* hibjb, const float* We2, const float* be2, float* scb)
{
    __shared__ __align__(16) char smem[34816];
    const int bid = blockIdx.x;
    if (bid < 512) {                       // final attn: grid (16,8,4); f32 out dead
        attn_dev<4>(smem, qkvb, nullptr, attnb_b, 256, 1536,
                    bid % 16, (bid / 16) % 8, bid / 128);
    } else {                               // scores: grid (8,8,4)
        const int r = bid - 512;
        scores_dev(smem, hibjb, 1024, 0, We2, be2, scb,
                   r % 8, (r / 8) % 8, r / 64);
    }
}

__global__ __launch_bounds__(256) void pack_topk_mfma(
    const float* scb, float* out_sparse,
    const unsigned short* attnb_b, const unsigned short* wsoT,
    const float* bs_o, float* out_att)
{
    const int bid = blockIdx.x;
    if (bid < 256) {                       // topk: 4 rows/block (wave/row)
        topk_wave(scb, out_sparse, bid * 4 + (threadIdx.x >> 6));
    } else {                               // mfma o: grid (8,8)
        const int r = bid - 256;
        mfma_dev(attnb_b, wsoT, bs_o, out_att, 1024, 512, 512, 512,
                 r % 8, r / 8);
    }
}

// ---------------------------------------------------------------------------
extern "C" void kernel_launch(void* const* d_in, const int* in_sizes, int n_in,
                              void* d_out, int out_size, void* d_ws, size_t ws_size,
                              hipStream_t stream)
{
    const float* x      = (const float*)d_in[0];
    const float* Wqkv   = (const float*)d_in[2];
    const float* bqkv   = (const float*)d_in[3];
    const float* Wo     = (const float*)d_in[4];
    const float* bo     = (const float*)d_in[5];
    const float* Wp1    = (const float*)d_in[6];
    const float* bp1    = (const float*)d_in[7];
    const float* Wp2    = (const float*)d_in[8];
    const float* bp2    = (const float*)d_in[9];
    const float* Wfuse  = (const float*)d_in[10];
    const float* bfuse  = (const float*)d_in[11];
    const float* ln_g   = (const float*)d_in[12];
    const float* ln_b   = (const float*)d_in[13];
    const float* We1    = (const float*)d_in[14];
    const float* be1    = (const float*)d_in[15];
    const float* We2    = (const float*)d_in[16];
    const float* be2    = (const float*)d_in[17];
    const float* Ws_qkv = (const float*)d_in[18];
    const float* bs_qkv = (const float*)d_in[19];
    const float* Ws_o   = (const float*)d_in[20];
    const float* bs_o   = (const float*)d_in[21];

    float* out_att    = (float*)d_out;               // 4*256*512
    float* out_sparse = out_att + 4 * 256 * 512;     // 4*256*256

    // workspace layout (floats)
    float* ws    = (float*)d_ws;
    float* qkvb  = ws;                    // 1,572,864 (qkv activations only)
    float* attnb = qkvb + 1572864;        //   524,288
    float* lvls  = attnb + 524288;        //   917,504 (lvl0 | lvl1 | lvl2)
    float* poolb = lvls + 917504;         //   131,072
    float* curb  = poolb + 131072;        //   262,144
    float* hier  = curb + 262144;         //   524,288
    float* scb   = hier + 524288;         //   262,144
    float* hibjb = scb + 262144;          // 1,048,576 [1024][1024] (hi|hj)
    float* ybuf  = hibjb;                 // alias: fuse y (dead before We1)
    unsigned short* hier_b  = (unsigned short*)(hibjb + 1048576);  // 524,288
    unsigned short* attnb_b = hier_b + 524288;                     // 524,288
    unsigned short* wqkvT   = attnb_b + 524288;                    // 786,432
    unsigned short* wsoT    = wqkvT + 786432;                      // 262,144

    float* lvl0 = lvls;
    float* lvl1 = lvls + 1024 * 512;
    float* lvl2 = lvls + 1536 * 512;

    auto G64 = [&](const float* A, const float* W, const float* bias, float* C,
                   int M, int N, int K, int flags, int wmode) {
        gemm_v6<64><<<dim3(N / 64, M / 64), 256, 0, stream>>>(
            A, W, bias, C, M, N, K, flags, wmode);
    };
    auto G32 = [&](const float* A, const float* W, const float* bias, float* C,
                   int M, int N, int K, int flags, int wmode) {
        gemm_v6<32><<<dim3(N / 64, M / 32), 256, 0, stream>>>(
            A, W, bias, C, M, N, K, flags, wmode);
    };

    // D1: qkv l0  ||  both weight cvt->bf16^T
    pack_qkv_cvt<<<640, 256, 0, stream>>>(x, Wqkv, bqkv, qkvb,
                                          Ws_qkv, wqkvT, Ws_o, wsoT);
    // D2-D3
    attn_v3<4><<<dim3(16, 8, 4), 256, 0, stream>>>(qkvb, attnb, nullptr, 256, 1536);
    G32(attnb, Wo, bo, lvl0, 1024, 512, 512, 0, 0);
    // D4: Wp1 l0 (relu+pool) || fuse segment 0
    pack_wp1_fuse<<<256, 256, 0, stream>>>(lvl0, Wp1, bp1, poolb,
                                           Wfuse, ybuf, 1024, 1024, 128);
    // D5
    G32(poolb, Wp2, bp2, curb, 512, 512, 256, 0, 0);

    // ---- Level 1 ----
    G64(curb, Wqkv + 512 * 1536, bqkv + 1536, qkvb, 512, 1536, 512, 0, 0);
    attn_v3<2><<<dim3(8, 8, 4), 256, 0, stream>>>(qkvb, attnb, nullptr, 128, 1536);
    G32(attnb, Wo + 512 * 512, bo + 512, lvl1, 512, 512, 512, 0, 0);
    // D9: Wp1 l1 || fuse segment 1
    pack_wp1_fuse<<<128, 256, 0, stream>>>(lvl1, Wp1 + 512 * 256, bp1 + 256, poolb,
                                           Wfuse + 262144, ybuf + 1024 * 512,
                                           512, 512, 64);
    G32(poolb, Wp2 + 256 * 512, bp2 + 512, curb, 256, 512, 256, 0, 0);

    // ---- Level 2 ----
    G32(curb, Wqkv + 2 * 512 * 1536, bqkv + 2 * 1536, qkvb, 256, 1536, 512, 0, 0);
    attn_v3<1><<<dim3(4, 8, 4), 256, 0, stream>>>(qkvb, attnb, nullptr, 64, 1536);
    G32(attnb, Wo + 2 * 512 * 512, bo + 2 * 512, lvl2, 256, 512, 512, 0, 0);
    // D14: fuse segment 2
    G64(lvl2, Wfuse + 524288, nullptr, ybuf + 1536 * 512, 256, 512, 512, 0, 0);

    // D15: LN (emits f32 + bf16 hier)
    ln3_k<<<256, 256, 0, stream>>>(ybuf, bfuse, ln_g, ln_b, hier, hier_b);

    // D16: We1 (f32, score path) || mfma final-qkv (bf16)
    pack_we1_mfma<<<448, 256, 0, stream>>>(hier, We1, be1, hibjb,
                                           hier_b, wqkvT, bs_qkv, qkvb);
    // D17: final attn || scores
    pack_attnF_scores<<<768, 256, 0, stream>>>(qkvb, attnb_b,
                                               hibjb, We2, be2, scb);
    // D18: topk || mfma o-proj
    pack_topk_mfma<<<320, 256, 0, stream>>>(scb, out_sparse,
                                            attnb_b, wsoT, bs_o, out_att);
}

// Round 17
// 463.048 us; speedup vs baseline: 1.1197x; 1.1197x over previous
//
#include <hip/hip_runtime.h>
#include <math.h>

// Problem constants: B=4, N=256, D=512, H=8, HD=64, L=3, K_SPARSE=25, EPS=1e-5

typedef __attribute__((ext_vector_type(8))) short bf16x8;
typedef __attribute__((ext_vector_type(4))) float f32x4;
typedef __attribute__((ext_vector_type(8))) unsigned short ushort8v;

__device__ __forceinline__ unsigned short f2bf(float x) {
    union { float f; unsigned int u; } c; c.f = x;
    unsigned int r = (c.u + 0x7fffu + ((c.u >> 16) & 1u)) >> 16;
    return (unsigned short)r;
}

// ---------------------------------------------------------------------------
// GEMM device body (f32): C[M,N] = act(A[M,K] @ W[K,N] + bias).
// TM=64: 4 rows x 4 cols/thread; TM=32: 2 rows x 4 cols.
// flags: 1 = relu, 2 = pool. wmode: 0 none; 2 = we1-split.
// ---------------------------------------------------------------------------
template <int TM>
__device__ __forceinline__ void gemm_dev(
    char* smem, const float* __restrict__ A, const float* __restrict__ W,
    const float* __restrict__ bias, float* __restrict__ C,
    int M, int N, int K, int flags, int wmode, int bx, int by)
{
    constexpr int RT = TM / 16;
    float (*As)[TM + 4] = (float (*)[TM + 4])smem;
    float (*Ws)[68] = (float (*)[68])(smem + 16 * (TM + 4) * sizeof(float));

    const int tid = threadIdx.x;
    const int tx = tid & 15, ty = tid >> 4;
    const int bm = by * TM, bn = bx * 64;

    const float* Wp = W;
    const float* bp = bias;
    int wn = N, wcol = bn;
    if (wmode == 2) {
        if (bn >= 512) Wp += 262144; else bp = nullptr;
        wn = 512; wcol = bn & 511;
    }

    constexpr int AV = (TM == 64) ? 4 : 2;
    const int ar = (TM == 64) ? (tid >> 2) : (tid >> 3);
    const int ac = (TM == 64) ? ((tid & 3) << 2) : ((tid & 7) << 1);
    const int wr = tid >> 4;
    const int wc = (tid & 15) << 2;

    const float* Aptr = A + (size_t)(bm + ar) * K + ac;
    const float* Wptr = Wp + (size_t)wr * wn + wcol + wc;

    float acc[RT][4] = {};
    float ra[AV], rw[4];

#define LOADREGS(k0_) do {                                                   \
        const float* ap_ = Aptr + (k0_);                                     \
        if constexpr (TM == 64) {                                            \
            float4 v_ = *(const float4*)ap_;                                 \
            ra[0]=v_.x; ra[1]=v_.y; ra[2]=v_.z; ra[3]=v_.w;                  \
        } else {                                                             \
            float2 v_ = *(const float2*)ap_; ra[0]=v_.x; ra[1]=v_.y;         \
        }                                                                    \
        float4 w_ = *(const float4*)(Wptr + (size_t)(k0_) * wn);             \
        rw[0]=w_.x; rw[1]=w_.y; rw[2]=w_.z; rw[3]=w_.w; } while (0)

    LOADREGS(0);

    for (int k0 = 0; k0 < K; k0 += 16) {
        if (k0) __syncthreads();
        #pragma unroll
        for (int u = 0; u < AV; ++u) As[ac + u][ar] = ra[u];
        #pragma unroll
        for (int u = 0; u < 4; ++u) Ws[wr][wc + u] = rw[u];
        __syncthreads();

        if (k0 + 16 < K) LOADREGS(k0 + 16);

        #pragma unroll
        for (int kk = 0; kk < 16; ++kk) {
            float a[RT];
            if constexpr (RT == 4) {
                float4 t = *(const float4*)&As[kk][ty * 4];
                a[0]=t.x; a[1]=t.y; a[2]=t.z; a[3]=t.w;
            } else {
                float2 t = *(const float2*)&As[kk][ty * 2];
                a[0]=t.x; a[1]=t.y;
            }
            float4 tw = *(const float4*)&Ws[kk][tx * 4];
            float w[4] = {tw.x, tw.y, tw.z, tw.w};
            #pragma unroll
            for (int i = 0; i < RT; ++i)
                #pragma unroll
                for (int j = 0; j < 4; ++j)
                    acc[i][j] = fmaf(a[i], w[j], acc[i][j]);
        }
    }
#undef LOADREGS

    #pragma unroll
    for (int j = 0; j < 4; ++j) {
        const int cn = bn + tx * 4 + j;
        const float bv = bp ? bp[wcol + tx * 4 + j] : 0.f;
        if (flags & 2) {
            #pragma unroll
            for (int pi = 0; pi < RT / 2; ++pi) {
                float f0 = acc[2 * pi][j] + bv;
                float f1 = acc[2 * pi + 1][j] + bv;
                if (flags & 1) { f0 = fmaxf(f0, 0.f); f1 = fmaxf(f1, 0.f); }
                int prow = ((bm + ty * RT) >> 1) + pi;
                C[(size_t)prow * N + cn] = (f0 + f1) * 0.5f;
            }
        } else {
            #pragma unroll
            for (int i = 0; i < RT; ++i) {
                float f = acc[i][j] + bv;
                if (flags & 1) f = fmaxf(f, 0.f);
                C[(size_t)(bm + ty * RT + i) * N + cn] = f;
            }
        }
    }
}

template <int TM>
__global__ __launch_bounds__(256) void gemm_v6(
    const float* __restrict__ A, const float* __restrict__ W,
    const float* __restrict__ bias, float* __restrict__ C,
    int M, int N, int K, int flags, int wmode)
{
    constexpr int SB = (TM == 64) ? 8704 : 6656;
    __shared__ __align__(16) char smem[SB];
    gemm_dev<TM>(smem, A, W, bias, C, M, N, K, flags, wmode, blockIdx.x, blockIdx.y);
}

// ---------------------------------------------------------------------------
// Transpose + f32->bf16 device body: Wt[N][K] = W[K][N]. 64x64 tiles.
// ---------------------------------------------------------------------------
__device__ __forceinline__ void cvt_dev(
    char* smem, const float* __restrict__ W, unsigned short* __restrict__ Wt,
    int K, int N, int bx, int by)
{
    unsigned short (*t)[72] = (unsigned short (*)[72])smem;
    const int n0 = bx * 64, k0 = by * 64;
    const int tid = threadIdx.x;
    const int rr = tid >> 4, c4 = (tid & 15) << 2;
    #pragma unroll
    for (int u = 0; u < 4; ++u) {
        const float4 v = *(const float4*)(W + (size_t)(k0 + rr + u * 16) * N + n0 + c4);
        t[c4 + 0][rr + u * 16] = f2bf(v.x);
        t[c4 + 1][rr + u * 16] = f2bf(v.y);
        t[c4 + 2][rr + u * 16] = f2bf(v.z);
        t[c4 + 3][rr + u * 16] = f2bf(v.w);
    }
    __syncthreads();
    const int orow = tid >> 2, oc = (tid & 3) << 4;
    unsigned short* dst = Wt + (size_t)(n0 + orow) * K + k0 + oc;
    *(ushort8v*)(dst + 0) = *(const ushort8v*)&t[orow][oc + 0];
    *(ushort8v*)(dst + 8) = *(const ushort8v*)&t[orow][oc + 8];
}

// ---------------------------------------------------------------------------
// MFMA bf16 GEMM device body (no LDS): C = A(bf16) @ Bt^T + bias.
// Block 256 = 4 waves; wave tile 32x64; block tile 128x64.
// ---------------------------------------------------------------------------
__device__ __forceinline__ void mfma_dev(
    const unsigned short* __restrict__ Ab, const unsigned short* __restrict__ Bt,
    const float* __restrict__ bias, float* __restrict__ C,
    int M, int N, int K, int ldc, int bx, int by)
{
    const int lane = threadIdx.x & 63;
    const int wv = threadIdx.x >> 6;
    const int bn = bx * 64;
    const int bm = by * 128 + wv * 32;
    const int l15 = lane & 15;
    const int kb = (lane >> 4) * 8;

    const unsigned short* a0p = Ab + (size_t)(bm + l15) * K + kb;
    const unsigned short* a1p = a0p + (size_t)16 * K;
    const unsigned short* bp0 = Bt + (size_t)(bn + l15) * K + kb;

    f32x4 acc[2][4];
    #pragma unroll
    for (int i = 0; i < 2; ++i)
        #pragma unroll
        for (int j = 0; j < 4; ++j)
            acc[i][j] = (f32x4){0.f, 0.f, 0.f, 0.f};

    for (int k0 = 0; k0 < K; k0 += 32) {
        const bf16x8 a0 = *(const bf16x8*)(a0p + k0);
        const bf16x8 a1 = *(const bf16x8*)(a1p + k0);
        #pragma unroll
        for (int nf = 0; nf < 4; ++nf) {
            const bf16x8 b = *(const bf16x8*)(bp0 + (size_t)nf * 16 * K + k0);
            acc[0][nf] = __builtin_amdgcn_mfma_f32_16x16x32_bf16(a0, b, acc[0][nf], 0, 0, 0);
            acc[1][nf] = __builtin_amdgcn_mfma_f32_16x16x32_bf16(a1, b, acc[1][nf], 0, 0, 0);
        }
    }

    const int r0 = (lane >> 4) * 4;
    #pragma unroll
    for (int mf = 0; mf < 2; ++mf)
        #pragma unroll
        for (int nf = 0; nf < 4; ++nf) {
            const int col = bn + nf * 16 + l15;
            const float bv = bias ? bias[col] : 0.f;
            #pragma unroll
            for (int r = 0; r < 4; ++r) {
                const int row = bm + mf * 16 + r0 + r;
                C[(size_t)row * ldc + col] = acc[mf][nf][r] + bv;
            }
        }
}

// ---------------------------------------------------------------------------
// Fused MHA device body (R14-proven). Block = (16 q-rows, h, b), 4 waves;
// wave owns 4 q-rows. NT = n/64. Q staged in LDS (b128 broadcast reads);
// K/V staged in LDS (V transposed). out (f32) / outb (bf16) both optional.
// LDS: q[16][64] 4096 + kv[64][68] 17408 + p[16][256] 16384 = 37888 B.
// ---------------------------------------------------------------------------
template <int NT>
__device__ __forceinline__ void attn_dev(
    char* smem, const float* __restrict__ qkv, float* __restrict__ out,
    unsigned short* __restrict__ outb, int n, int qstride,
    int bx, int by, int bz)
{
    float (*q_lds)[64]  = (float (*)[64])smem;
    float (*kv_lds)[68] = (float (*)[68])(smem + 4096);
    float (*p_lds)[256] = (float (*)[256])(smem + 4096 + 17408);

    const int lane = threadIdx.x & 63;
    const int w    = threadIdx.x >> 6;
    const int h = by, b = bz;
    const int q0 = bx * 16;
    const size_t base = (size_t)b * n * qstride;

    {
        int r = threadIdx.x >> 4, c4 = (threadIdx.x & 15) << 2;
        float4 v = *(const float4*)(qkv + base + (size_t)(q0 + r) * qstride + h * 64 + c4);
        q_lds[r][c4 + 0] = v.x; q_lds[r][c4 + 1] = v.y;
        q_lds[r][c4 + 2] = v.z; q_lds[r][c4 + 3] = v.w;
    }

    const int r0 = w * 4;
    const int sr = threadIdx.x >> 2;
    const int sq = threadIdx.x & 3;

    float s[4][NT];

    #pragma unroll
    for (int t = 0; t < NT; ++t) {
        const int j0 = t * 64;
        __syncthreads();
        {
            const float* src = qkv + base + (size_t)(j0 + sr) * qstride + 512 + h * 64;
            #pragma unroll
            for (int u = 0; u < 4; ++u) {
                int c = u * 4 + sq;
                float4 v = *(const float4*)(src + c * 4);
                *(float4*)&kv_lds[sr][c * 4] = v;
            }
        }
        __syncthreads();
        float c0 = 0.f, c1 = 0.f, c2 = 0.f, c3 = 0.f;
        #pragma unroll
        for (int d = 0; d < 64; d += 4) {
            const float4 kv = *(const float4*)&kv_lds[lane][d];
            const float4 qa = *(const float4*)&q_lds[r0 + 0][d];
            const float4 qb = *(const float4*)&q_lds[r0 + 1][d];
            const float4 qc = *(const float4*)&q_lds[r0 + 2][d];
            const float4 qd = *(const float4*)&q_lds[r0 + 3][d];
            c0 = fmaf(qa.x, kv.x, c0); c0 = fmaf(qa.y, kv.y, c0);
            c0 = fmaf(qa.z, kv.z, c0); c0 = fmaf(qa.w, kv.w, c0);
            c1 = fmaf(qb.x, kv.x, c1); c1 = fmaf(qb.y, kv.y, c1);
            c1 = fmaf(qb.z, kv.z, c1); c1 = fmaf(qb.w, kv.w, c1);
            c2 = fmaf(qc.x, kv.x, c2); c2 = fmaf(qc.y, kv.y, c2);
            c2 = fmaf(qc.z, kv.z, c2); c2 = fmaf(qc.w, kv.w, c2);
            c3 = fmaf(qd.x, kv.x, c3); c3 = fmaf(qd.y, kv.y, c3);
            c3 = fmaf(qd.z, kv.z, c3); c3 = fmaf(qd.w, kv.w, c3);
        }
        s[0][t] = c0 * 0.125f; s[1][t] = c1 * 0.125f;
        s[2][t] = c2 * 0.125f; s[3][t] = c3 * 0.125f;
    }

    double inv[4];
    #pragma unroll
    for (int qr = 0; qr < 4; ++qr) {
        float m = s[qr][0];
        #pragma unroll
        for (int t = 1; t < NT; ++t) m = fmaxf(m, s[qr][t]);
        #pragma unroll
        for (int off = 32; off; off >>= 1) m = fmaxf(m, __shfl_xor(m, off));
        double sum = 0.0;
        #pragma unroll
        for (int t = 0; t < NT; ++t) {
            float p = expf(s[qr][t] - m);
            p_lds[r0 + qr][t * 64 + lane] = p;
            sum += (double)p;
        }
        #pragma unroll
        for (int off = 32; off; off >>= 1) sum += __shfl_xor(sum, off);
        inv[qr] = 1.0 / sum;
    }

    float o0 = 0.f, o1 = 0.f, o2 = 0.f, o3 = 0.f;
    #pragma unroll
    for (int t = 0; t < NT; ++t) {
        const int j0 = t * 64;
        __syncthreads();
        {
            const float* src = qkv + base + (size_t)(j0 + sr) * qstride + 1024 + h * 64;
            #pragma unroll
            for (int u = 0; u < 4; ++u) {
                int c = u * 4 + sq;
                float4 v = *(const float4*)(src + c * 4);
                kv_lds[c * 4 + 0][sr] = v.x;
                kv_lds[c * 4 + 1][sr] = v.y;
                kv_lds[c * 4 + 2][sr] = v.z;
                kv_lds[c * 4 + 3][sr] = v.w;
            }
        }
        __syncthreads();
        #pragma unroll
        for (int jl = 0; jl < 64; jl += 4) {
            const float4 vv = *(const float4*)&kv_lds[lane][jl];
            const float4 pa = *(const float4*)&p_lds[r0 + 0][t * 64 + jl];
            const float4 pb = *(const float4*)&p_lds[r0 + 1][t * 64 + jl];
            const float4 pc = *(const float4*)&p_lds[r0 + 2][t * 64 + jl];
            const float4 pd = *(const float4*)&p_lds[r0 + 3][t * 64 + jl];
            o0 = fmaf(pa.x, vv.x, o0); o0 = fmaf(pa.y, vv.y, o0);
            o0 = fmaf(pa.z, vv.z, o0); o0 = fmaf(pa.w, vv.w, o0);
            o1 = fmaf(pb.x, vv.x, o1); o1 = fmaf(pb.y, vv.y, o1);
            o1 = fmaf(pb.z, vv.z, o1); o1 = fmaf(pb.w, vv.w, o1);
            o2 = fmaf(pc.x, vv.x, o2); o2 = fmaf(pc.y, vv.y, o2);
            o2 = fmaf(pc.z, vv.z, o2); o2 = fmaf(pc.w, vv.w, o2);
            o3 = fmaf(pd.x, vv.x, o3); o3 = fmaf(pd.y, vv.y, o3);
            o3 = fmaf(pd.z, vv.z, o3); o3 = fmaf(pd.w, vv.w, o3);
        }
    }
    const size_t obase = ((size_t)(b * n + q0 + r0)) * 512 + h * 64 + lane;
    const float r0v = (float)((double)o0 * inv[0]);
    const float r1v = (float)((double)o1 * inv[1]);
    const float r2v = (float)((double)o2 * inv[2]);
    const float r3v = (float)((double)o3 * inv[3]);
    if (out) {
        out[obase + 0 * 512] = r0v;
        out[obase + 1 * 512] = r1v;
        out[obase + 2 * 512] = r2v;
        out[obase + 3 * 512] = r3v;
    }
    if (outb) {
        outb[obase + 0 * 512] = f2bf(r0v);
        outb[obase + 1 * 512] = f2bf(r1v);
        outb[obase + 2 * 512] = f2bf(r2v);
        outb[obase + 3 * 512] = f2bf(r3v);
    }
}

template <int NT>
__global__ __launch_bounds__(256) void attn_v3(
    const float* __restrict__ qkv, float* __restrict__ out,
    unsigned short* __restrict__ outb, int n, int qstride)
{
    __shared__ __align__(16) char smem[37888];
    attn_dev<NT>(smem, qkv, out, outb, n, qstride, blockIdx.x, blockIdx.y, blockIdx.z);
}

// ---------------------------------------------------------------------------
// Edge scores device body v5: z[i,j] = sum_d relu(hi[i,d]+hj[j,d])*w2[d].
// f32 accumulation within each 128-deep chunk, f64 across chunks. We2
// scalar f32 loads (loop-counter index -> true SGPR path).
// ---------------------------------------------------------------------------
__device__ __forceinline__ void scores_dev(
    char* smem, const float* __restrict__ hq, int stride, int off,
    const float* __restrict__ We2, const float* __restrict__ be2,
    float* __restrict__ S, int bx, int by, int bz)
{
    float (*Hi)[34] = (float (*)[34])smem;             // 17408 B
    float (*Hj)[34] = (float (*)[34])(smem + 17408);   // 17408 B
    const int b = bz;
    const int i0 = by * 32, j0 = bx * 32;
    const int tid = threadIdx.x;
    const int tx = tid & 15, ty = tid >> 4;

    const int si = tid >> 3;
    const int sd = (tid & 7) << 2;

    const float* hip = hq + (size_t)(b * 256 + i0 + si) * stride + off + sd;
    const float* hjp = hq + (size_t)(b * 256 + j0 + si) * stride + off + 512 + sd;

    double a00 = 0.0, a01 = 0.0, a10 = 0.0, a11 = 0.0;

    for (int k0 = 0; k0 < 512; k0 += 128) {
        __syncthreads();
        #pragma unroll
        for (int u = 0; u < 4; ++u) {
            const int dch = u * 32 + sd;
            float4 v = *(const float4*)(hip + k0 + u * 32);
            Hi[dch + 0][si] = v.x; Hi[dch + 1][si] = v.y;
            Hi[dch + 2][si] = v.z; Hi[dch + 3][si] = v.w;
            float4 w = *(const float4*)(hjp + k0 + u * 32);
            Hj[dch + 0][si] = w.x; Hj[dch + 1][si] = w.y;
            Hj[dch + 2][si] = w.z; Hj[dch + 3][si] = w.w;
        }
        __syncthreads();
        float c00 = 0.f, c01 = 0.f, c10 = 0.f, c11 = 0.f;
        #pragma unroll 16
        for (int kk = 0; kk < 128; ++kk) {
            const float wv = We2[k0 + kk];   // wave-uniform -> s_load
            const float2 hi = *(const float2*)&Hi[kk][ty * 2];
            const float2 hj = *(const float2*)&Hj[kk][tx * 2];
            c00 = fmaf(fmaxf(hi.x + hj.x, 0.f), wv, c00);
            c01 = fmaf(fmaxf(hi.x + hj.y, 0.f), wv, c01);
            c10 = fmaf(fmaxf(hi.y + hj.x, 0.f), wv, c10);
            c11 = fmaf(fmaxf(hi.y + hj.y, 0.f), wv, c11);
        }
        a00 += (double)c00; a01 += (double)c01;
        a10 += (double)c10; a11 += (double)c11;
    }

    const double bb = (double)be2[0];
    const int gi0 = i0 + ty * 2, gj0 = j0 + tx * 2;
    double zz[2][2] = {{a00, a01}, {a10, a11}};
    #pragma unroll
    for (int ii = 0; ii < 2; ++ii)
        #pragma unroll
        for (int jj = 0; jj < 2; ++jj) {
            double z = zz[ii][jj] + bb;
            float sc_ = (float)(1.0 / (1.0 + exp(-z)));
            if (gi0 + ii == gj0 + jj) sc_ = 0.f;
            S[(size_t)(b * 256 + gi0 + ii) * 256 + gj0 + jj] = sc_;
        }
}

// ---------------------------------------------------------------------------
// Top-k(25) one-hot per row of 256, one WAVE per row (ties -> lower index).
// ---------------------------------------------------------------------------
__device__ __forceinline__ void topk_wave(
    const float* __restrict__ S, float* __restrict__ out, int row)
{
    const int lane = threadIdx.x & 63;
    float v[4]; int sel[4] = {0, 0, 0, 0};
    #pragma unroll
    for (int t = 0; t < 4; ++t) v[t] = S[(size_t)row * 256 + t * 64 + lane];
    for (int it = 0; it < 25; ++it) {
        float bv = v[0]; int bi = lane;
        #pragma unroll
        for (int t = 1; t < 4; ++t) {
            int idx = t * 64 + lane;
            if (v[t] > bv) { bv = v[t]; bi = idx; }
        }
        #pragma unroll
        for (int off = 32; off; off >>= 1) {
            float ov = __shfl_xor(bv, off);
            int   oi = __shfl_xor(bi, off);
            if (ov > bv || (ov == bv && oi < bi)) { bv = ov; bi = oi; }
        }
        if ((bi & 63) == lane) { int t = bi >> 6; sel[t] = 1; v[t] = -INFINITY; }
    }
    #pragma unroll
    for (int t = 0; t < 4; ++t)
        out[(size_t)row * 256 + t * 64 + lane] = (float)sel[t];
}

// ---------------------------------------------------------------------------
// Fused 3-way add + bias + relu + LayerNorm, one WAVE per row (4 rows/block).
// ---------------------------------------------------------------------------
__global__ __launch_bounds__(256) void ln3_k(
    const float* __restrict__ y, const float* __restrict__ bf,
    const float* __restrict__ g, const float* __restrict__ bta,
    float* __restrict__ out, unsigned short* __restrict__ outb)
{
    const int r = blockIdx.x * 4 + (threadIdx.x >> 6);
    const int lane = threadIdx.x & 63;
    const int b = r >> 8, i = r & 255;
    const float* y0 = y + (size_t)r * 512;
    const float* y1 = y + (size_t)(1024 + b * 128 + (i >> 1)) * 512;
    const float* y2 = y + (size_t)(1536 + b * 64 + (i >> 2)) * 512;
    double v[8];
    double sum = 0.0;
    #pragma unroll
    for (int t = 0; t < 8; ++t) {
        int d = t * 64 + lane;
        double s = (double)y0[d] + (double)y1[d] + (double)y2[d] + (double)bf[d];
        s = s > 0.0 ? s : 0.0;
        v[t] = s; sum += s;
    }
    #pragma unroll
    for (int off = 32; off; off >>= 1) sum += __shfl_xor(sum, off);
    const double mean = sum * (1.0 / 512.0);
    double ss = 0.0;
    #pragma unroll
    for (int t = 0; t < 8; ++t) { double d = v[t] - mean; ss += d * d; }
    #pragma unroll
    for (int off = 32; off; off >>= 1) ss += __shfl_xor(ss, off);
    const double rstd = 1.0 / sqrt(ss * (1.0 / 512.0) + 1e-5);
    #pragma unroll
    for (int t = 0; t < 8; ++t) {
        int d = t * 64 + lane;
        float f = (float)((v[t] - mean) * rstd * (double)g[d] + (double)bta[d]);
        out[(size_t)r * 512 + d] = f;
        outb[(size_t)r * 512 + d] = f2bf(f);
    }
}

// ---------------------------------------------------------------------------
// Packed dispatches (block-range union of mutually independent ops)
// ---------------------------------------------------------------------------
__global__ __launch_bounds__(256) void pack_qkv_cvt(
    const float* x, const float* Wqkv, const float* bqkv, float* qkvb,
    const float* Wsqkv, unsigned short* wqkvT,
    const float* Wso, unsigned short* wsoT)
{
    __shared__ __align__(16) char smem[9216];
    const int bid = blockIdx.x;
    if (bid < 384) {                       // qkv l0: grid (24,16)
        gemm_dev<64>(smem, x, Wqkv, bqkv, qkvb, 1024, 1536, 512, 0, 0,
                     bid % 24, bid / 24);
    } else if (bid < 576) {                // cvt Ws_qkv: grid (24,8)
        const int r = bid - 384;
        cvt_dev(smem, Wsqkv, wqkvT, 512, 1536, r % 24, r / 24);
    } else {                               // cvt Ws_o: grid (8,8)
        const int r = bid - 576;
        cvt_dev(smem, Wso, wsoT, 512, 512, r % 8, r / 8);
    }
}

// Wp1 (relu+pool) || fuse segment. nb_w = Wp1 blocks; fuse grid (8, Mf/64).
__global__ __launch_bounds__(256) void pack_wp1_fuse(
    const float* lvl, const float* Wp1, const float* bp1, float* poolb,
    const float* Wfseg, float* ydst, int Mw, int Mf, int nb_w)
{
    __shared__ __align__(16) char smem[8704];
    const int bid = blockIdx.x;
    if (bid < nb_w) {
        gemm_dev<32>(smem, lvl, Wp1, bp1, poolb, Mw, 256, 512, 3, 0,
                     bid % 4, bid / 4);
    } else {
        const int r = bid - nb_w;
        gemm_dev<64>(smem, lvl, Wfseg, nullptr, ydst, Mf, 512, 512, 0, 0,
                     r % 8, r / 8);
    }
}

__global__ __launch_bounds__(256) void pack_we1_mfma(
    const float* hier, const float* We1, const float* be1, float* hibjb,
    const unsigned short* hier_b, const unsigned short* wqkvT,
    const float* bs_qkv, float* qkvb)
{
    __shared__ __align__(16) char smem[8704];
    const int bid = blockIdx.x;
    if (bid < 256) {                       // We1: grid (16,16), wmode 2
        gemm_dev<64>(smem, hier, We1, be1, hibjb, 1024, 1024, 512, 0, 2,
                     bid % 16, bid / 16);
    } else {                               // mfma qkv: grid (24,8)
        const int r = bid - 256;
        mfma_dev(hier_b, wqkvT, bs_qkv, qkvb, 1024, 1536, 512, 1536,
                 r % 24, r / 24);
    }
}

__global__ __launch_bounds__(256) void pack_attnF_scores(
    const float* qkvb, unsigned short* attnb_b,
    const float* hibjb, const float* We2, const float* be2, float* scb)
{
    __shared__ __align__(16) char smem[37888];
    const int bid = blockIdx.x;
    if (bid < 512) {                       // final attn: grid (16,8,4); f32 out dead
        attn_dev<4>(smem, qkvb, nullptr, attnb_b, 256, 1536,
                    bid % 16, (bid / 16) % 8, bid / 128);
    } else {                               // scores: grid (8,8,4)
        const int r = bid - 512;
        scores_dev(smem, hibjb, 1024, 0, We2, be2, scb,
                   r % 8, (r / 8) % 8, r / 64);
    }
}

__global__ __launch_bounds__(256) void pack_topk_mfma(
    const float* scb, float* out_sparse,
    const unsigned short* attnb_b, const unsigned short* wsoT,
    const float* bs_o, float* out_att)
{
    const int bid = blockIdx.x;
    if (bid < 256) {                       // topk: 4 rows/block (wave/row)
        topk_wave(scb, out_sparse, bid * 4 + (threadIdx.x >> 6));
    } else {                               // mfma o: grid (8,8)
        const int r = bid - 256;
        mfma_dev(attnb_b, wsoT, bs_o, out_att, 1024, 512, 512, 512,
                 r % 8, r / 8);
    }
}

// ---------------------------------------------------------------------------
extern "C" void kernel_launch(void* const* d_in, const int* in_sizes, int n_in,
                              void* d_out, int out_size, void* d_ws, size_t ws_size,
                              hipStream_t stream)
{
    const float* x      = (const float*)d_in[0];
    const float* Wqkv   = (const float*)d_in[2];
    const float* bqkv   = (const float*)d_in[3];
    const float* Wo     = (const float*)d_in[4];
    const float* bo     = (const float*)d_in[5];
    const float* Wp1    = (const float*)d_in[6];
    const float* bp1    = (const float*)d_in[7];
    const float* Wp2    = (const float*)d_in[8];
    const float* bp2    = (const float*)d_in[9];
    const float* Wfuse  = (const float*)d_in[10];
    const float* bfuse  = (const float*)d_in[11];
    const float* ln_g   = (const float*)d_in[12];
    const float* ln_b   = (const float*)d_in[13];
    const float* We1    = (const float*)d_in[14];
    const float* be1    = (const float*)d_in[15];
    const float* We2    = (const float*)d_in[16];
    const float* be2    = (const float*)d_in[17];
    const float* Ws_qkv = (const float*)d_in[18];
    const float* bs_qkv = (const float*)d_in[19];
    const float* Ws_o   = (const float*)d_in[20];
    const float* bs_o   = (const float*)d_in[21];

    float* out_att    = (float*)d_out;               // 4*256*512
    float* out_sparse = out_att + 4 * 256 * 512;     // 4*256*256

    // workspace layout (floats)
    float* ws    = (float*)d_ws;
    float* qkvb  = ws;                    // 1,572,864 (qkv activations only)
    float* attnb = qkvb + 1572864;        //   524,288
    float* lvls  = attnb + 524288;        //   917,504 (lvl0 | lvl1 | lvl2)
    float* poolb = lvls + 917504;         //   131,072
    float* curb  = poolb + 131072;        //   262,144
    float* hier  = curb + 262144;         //   524,288
    float* scb   = hier + 524288;         //   262,144
    float* hibjb = scb + 262144;          // 1,048,576 [1024][1024] (hi|hj)
    float* ybuf  = hibjb;                 // alias: fuse y (dead before We1)
    unsigned short* hier_b  = (unsigned short*)(hibjb + 1048576);  // 524,288
    unsigned short* attnb_b = hier_b + 524288;                     // 524,288
    unsigned short* wqkvT   = attnb_b + 524288;                    // 786,432
    unsigned short* wsoT    = wqkvT + 786432;                      // 262,144

    float* lvl0 = lvls;
    float* lvl1 = lvls + 1024 * 512;
    float* lvl2 = lvls + 1536 * 512;

    auto G64 = [&](const float* A, const float* W, const float* bias, float* C,
                   int M, int N, int K, int flags, int wmode) {
        gemm_v6<64><<<dim3(N / 64, M / 64), 256, 0, stream>>>(
            A, W, bias, C, M, N, K, flags, wmode);
    };
    auto G32 = [&](const float* A, const float* W, const float* bias, float* C,
                   int M, int N, int K, int flags, int wmode) {
        gemm_v6<32><<<dim3(N / 64, M / 32), 256, 0, stream>>>(
            A, W, bias, C, M, N, K, flags, wmode);
    };

    // D1: qkv l0  ||  both weight cvt->bf16^T
    pack_qkv_cvt<<<640, 256, 0, stream>>>(x, Wqkv, bqkv, qkvb,
                                          Ws_qkv, wqkvT, Ws_o, wsoT);
    // D2-D3
    attn_v3<4><<<dim3(16, 8, 4), 256, 0, stream>>>(qkvb, attnb, nullptr, 256, 1536);
    G32(attnb, Wo, bo, lvl0, 1024, 512, 512, 0, 0);
    // D4: Wp1 l0 (relu+pool) || fuse segment 0
    pack_wp1_fuse<<<256, 256, 0, stream>>>(lvl0, Wp1, bp1, poolb,
                                           Wfuse, ybuf, 1024, 1024, 128);
    // D5
    G32(poolb, Wp2, bp2, curb, 512, 512, 256, 0, 0);

    // ---- Level 1 ----
    G64(curb, Wqkv + 512 * 1536, bqkv + 1536, qkvb, 512, 1536, 512, 0, 0);
    attn_v3<2><<<dim3(8, 8, 4), 256, 0, stream>>>(qkvb, attnb, nullptr, 128, 1536);
    G32(attnb, Wo + 512 * 512, bo + 512, lvl1, 512, 512, 512, 0, 0);
    // D9: Wp1 l1 || fuse segment 1
    pack_wp1_fuse<<<128, 256, 0, stream>>>(lvl1, Wp1 + 512 * 256, bp1 + 256, poolb,
                                           Wfuse + 262144, ybuf + 1024 * 512,
                                           512, 512, 64);
    G32(poolb, Wp2 + 256 * 512, bp2 + 512, curb, 256, 512, 256, 0, 0);

    // ---- Level 2 ----
    G32(curb, Wqkv + 2 * 512 * 1536, bqkv + 2 * 1536, qkvb, 256, 1536, 512, 0, 0);
    attn_v3<1><<<dim3(4, 8, 4), 256, 0, stream>>>(qkvb, attnb, nullptr, 64, 1536);
    G32(attnb, Wo + 2 * 512 * 512, bo + 2 * 512, lvl2, 256, 512, 512, 0, 0);
    // D14: fuse segment 2
    G64(lvl2, Wfuse + 524288, nullptr, ybuf + 1536 * 512, 256, 512, 512, 0, 0);

    // D15: LN (emits f32 + bf16 hier)
    ln3_k<<<256, 256, 0, stream>>>(ybuf, bfuse, ln_g, ln_b, hier, hier_b);

    // D16: We1 (f32, score path) || mfma final-qkv (bf16)
    pack_we1_mfma<<<448, 256, 0, stream>>>(hier, We1, be1, hibjb,
                                           hier_b, wqkvT, bs_qkv, qkvb);
    // D17: final attn || scores
    pack_attnF_scores<<<768, 256, 0, stream>>>(qkvb, attnb_b,
                                               hibjb, We2, be2, scb);
    // D18: topk || mfma o-proj
    pack_topk_mfma<<<320, 256, 0, stream>>>(scb, out_sparse,
                                            attnb_b, wsoT, bs_o, out_att);
}

// Round 18
// 348.310 us; speedup vs baseline: 1.4886x; 1.3294x over previous
//
#include <hip/hip_runtime.h>
#include <math.h>

// Problem constants: B=4, N=256, D=512, H=8, HD=64, L=3, K_SPARSE=25, EPS=1e-5
// R17: exact restoration of the R14 measured-good configuration (349 us).
// R15/R16 lesson: scores_v5 f32-chunk + out=nullptr specialization in the
// pack kernel triggered a 256-VGPR spill (FETCH/WRITE scratch storm).

typedef __attribute__((ext_vector_type(8))) short bf16x8;
typedef __attribute__((ext_vector_type(4))) float f32x4;
typedef __attribute__((ext_vector_type(8))) unsigned short ushort8v;

__device__ __forceinline__ unsigned short f2bf(float x) {
    union { float f; unsigned int u; } c; c.f = x;
    unsigned int r = (c.u + 0x7fffu + ((c.u >> 16) & 1u)) >> 16;
    return (unsigned short)r;
}

// ---------------------------------------------------------------------------
// GEMM device body (f32): C[M,N] = act(A[M,K] @ W[K,N] + bias).
// TM=64: 4 rows x 4 cols/thread; TM=32: 2 rows x 4 cols.
// flags: 1 = relu, 2 = pool. wmode: 0 none; 2 = we1-split.
// ---------------------------------------------------------------------------
template <int TM>
__device__ __forceinline__ void gemm_dev(
    char* smem, const float* __restrict__ A, const float* __restrict__ W,
    const float* __restrict__ bias, float* __restrict__ C,
    int M, int N, int K, int flags, int wmode, int bx, int by)
{
    constexpr int RT = TM / 16;
    float (*As)[TM + 4] = (float (*)[TM + 4])smem;
    float (*Ws)[68] = (float (*)[68])(smem + 16 * (TM + 4) * sizeof(float));

    const int tid = threadIdx.x;
    const int tx = tid & 15, ty = tid >> 4;
    const int bm = by * TM, bn = bx * 64;

    const float* Wp = W;
    const float* bp = bias;
    int wn = N, wcol = bn;
    if (wmode == 2) {
        if (bn >= 512) Wp += 262144; else bp = nullptr;
        wn = 512; wcol = bn & 511;
    }

    constexpr int AV = (TM == 64) ? 4 : 2;
    const int ar = (TM == 64) ? (tid >> 2) : (tid >> 3);
    const int ac = (TM == 64) ? ((tid & 3) << 2) : ((tid & 7) << 1);
    const int wr = tid >> 4;
    const int wc = (tid & 15) << 2;

    const float* Aptr = A + (size_t)(bm + ar) * K + ac;
    const float* Wptr = Wp + (size_t)wr * wn + wcol + wc;

    float acc[RT][4] = {};
    float ra[AV], rw[4];

#define LOADREGS(k0_) do {                                                   \
        const float* ap_ = Aptr + (k0_);                                     \
        if constexpr (TM == 64) {                                            \
            float4 v_ = *(const float4*)ap_;                                 \
            ra[0]=v_.x; ra[1]=v_.y; ra[2]=v_.z; ra[3]=v_.w;                  \
        } else {                                                             \
            float2 v_ = *(const float2*)ap_; ra[0]=v_.x; ra[1]=v_.y;         \
        }                                                                    \
        float4 w_ = *(const float4*)(Wptr + (size_t)(k0_) * wn);             \
        rw[0]=w_.x; rw[1]=w_.y; rw[2]=w_.z; rw[3]=w_.w; } while (0)

    LOADREGS(0);

    for (int k0 = 0; k0 < K; k0 += 16) {
        if (k0) __syncthreads();
        #pragma unroll
        for (int u = 0; u < AV; ++u) As[ac + u][ar] = ra[u];
        #pragma unroll
        for (int u = 0; u < 4; ++u) Ws[wr][wc + u] = rw[u];
        __syncthreads();

        if (k0 + 16 < K) LOADREGS(k0 + 16);

        #pragma unroll
        for (int kk = 0; kk < 16; ++kk) {
            float a[RT];
            if constexpr (RT == 4) {
                float4 t = *(const float4*)&As[kk][ty * 4];
                a[0]=t.x; a[1]=t.y; a[2]=t.z; a[3]=t.w;
            } else {
                float2 t = *(const float2*)&As[kk][ty * 2];
                a[0]=t.x; a[1]=t.y;
            }
            float4 tw = *(const float4*)&Ws[kk][tx * 4];
            float w[4] = {tw.x, tw.y, tw.z, tw.w};
            #pragma unroll
            for (int i = 0; i < RT; ++i)
                #pragma unroll
                for (int j = 0; j < 4; ++j)
                    acc[i][j] = fmaf(a[i], w[j], acc[i][j]);
        }
    }
#undef LOADREGS

    #pragma unroll
    for (int j = 0; j < 4; ++j) {
        const int cn = bn + tx * 4 + j;
        const float bv = bp ? bp[wcol + tx * 4 + j] : 0.f;
        if (flags & 2) {
            #pragma unroll
            for (int pi = 0; pi < RT / 2; ++pi) {
                float f0 = acc[2 * pi][j] + bv;
                float f1 = acc[2 * pi + 1][j] + bv;
                if (flags & 1) { f0 = fmaxf(f0, 0.f); f1 = fmaxf(f1, 0.f); }
                int prow = ((bm + ty * RT) >> 1) + pi;
                C[(size_t)prow * N + cn] = (f0 + f1) * 0.5f;
            }
        } else {
            #pragma unroll
            for (int i = 0; i < RT; ++i) {
                float f = acc[i][j] + bv;
                if (flags & 1) f = fmaxf(f, 0.f);
                C[(size_t)(bm + ty * RT + i) * N + cn] = f;
            }
        }
    }
}

template <int TM>
__global__ __launch_bounds__(256) void gemm_v6(
    const float* __restrict__ A, const float* __restrict__ W,
    const float* __restrict__ bias, float* __restrict__ C,
    int M, int N, int K, int flags, int wmode)
{
    constexpr int SB = (TM == 64) ? 8704 : 6656;
    __shared__ __align__(16) char smem[SB];
    gemm_dev<TM>(smem, A, W, bias, C, M, N, K, flags, wmode, blockIdx.x, blockIdx.y);
}

// ---------------------------------------------------------------------------
// Transpose + f32->bf16 device body: Wt[N][K] = W[K][N]. 64x64 tiles.
// ---------------------------------------------------------------------------
__device__ __forceinline__ void cvt_dev(
    char* smem, const float* __restrict__ W, unsigned short* __restrict__ Wt,
    int K, int N, int bx, int by)
{
    unsigned short (*t)[72] = (unsigned short (*)[72])smem;
    const int n0 = bx * 64, k0 = by * 64;
    const int tid = threadIdx.x;
    const int rr = tid >> 4, c4 = (tid & 15) << 2;
    #pragma unroll
    for (int u = 0; u < 4; ++u) {
        const float4 v = *(const float4*)(W + (size_t)(k0 + rr + u * 16) * N + n0 + c4);
        t[c4 + 0][rr + u * 16] = f2bf(v.x);
        t[c4 + 1][rr + u * 16] = f2bf(v.y);
        t[c4 + 2][rr + u * 16] = f2bf(v.z);
        t[c4 + 3][rr + u * 16] = f2bf(v.w);
    }
    __syncthreads();
    const int orow = tid >> 2, oc = (tid & 3) << 4;
    unsigned short* dst = Wt + (size_t)(n0 + orow) * K + k0 + oc;
    *(ushort8v*)(dst + 0) = *(const ushort8v*)&t[orow][oc + 0];
    *(ushort8v*)(dst + 8) = *(const ushort8v*)&t[orow][oc + 8];
}

// ---------------------------------------------------------------------------
// MFMA bf16 GEMM device body (no LDS): C = A(bf16) @ Bt^T + bias.
// Block 256 = 4 waves; wave tile 32x64; block tile 128x64.
// ---------------------------------------------------------------------------
__device__ __forceinline__ void mfma_dev(
    const unsigned short* __restrict__ Ab, const unsigned short* __restrict__ Bt,
    const float* __restrict__ bias, float* __restrict__ C,
    int M, int N, int K, int ldc, int bx, int by)
{
    const int lane = threadIdx.x & 63;
    const int wv = threadIdx.x >> 6;
    const int bn = bx * 64;
    const int bm = by * 128 + wv * 32;
    const int l15 = lane & 15;
    const int kb = (lane >> 4) * 8;

    const unsigned short* a0p = Ab + (size_t)(bm + l15) * K + kb;
    const unsigned short* a1p = a0p + (size_t)16 * K;
    const unsigned short* bp0 = Bt + (size_t)(bn + l15) * K + kb;

    f32x4 acc[2][4];
    #pragma unroll
    for (int i = 0; i < 2; ++i)
        #pragma unroll
        for (int j = 0; j < 4; ++j)
            acc[i][j] = (f32x4){0.f, 0.f, 0.f, 0.f};

    for (int k0 = 0; k0 < K; k0 += 32) {
        const bf16x8 a0 = *(const bf16x8*)(a0p + k0);
        const bf16x8 a1 = *(const bf16x8*)(a1p + k0);
        #pragma unroll
        for (int nf = 0; nf < 4; ++nf) {
            const bf16x8 b = *(const bf16x8*)(bp0 + (size_t)nf * 16 * K + k0);
            acc[0][nf] = __builtin_amdgcn_mfma_f32_16x16x32_bf16(a0, b, acc[0][nf], 0, 0, 0);
            acc[1][nf] = __builtin_amdgcn_mfma_f32_16x16x32_bf16(a1, b, acc[1][nf], 0, 0, 0);
        }
    }

    const int r0 = (lane >> 4) * 4;
    #pragma unroll
    for (int mf = 0; mf < 2; ++mf)
        #pragma unroll
        for (int nf = 0; nf < 4; ++nf) {
            const int col = bn + nf * 16 + l15;
            const float bv = bias ? bias[col] : 0.f;
            #pragma unroll
            for (int r = 0; r < 4; ++r) {
                const int row = bm + mf * 16 + r0 + r;
                C[(size_t)row * ldc + col] = acc[mf][nf][r] + bv;
            }
        }
}

// ---------------------------------------------------------------------------
// Fused MHA device body. Block = (16 q-rows, h, b), 4 waves; wave owns 4
// q-rows. NT = n/64. Q staged in LDS; b128 LDS reads; V staged transposed.
// Optional bf16 shadow output (outb != nullptr).
// LDS: q[16][64] 4096 + kv[64][68] 17408 + p[16][256] 16384 = 37888 B.
// ---------------------------------------------------------------------------
template <int NT>
__device__ __forceinline__ void attn_dev(
    char* smem, const float* __restrict__ qkv, float* __restrict__ out,
    unsigned short* __restrict__ outb, int n, int qstride,
    int bx, int by, int bz)
{
    float (*q_lds)[64]  = (float (*)[64])smem;
    float (*kv_lds)[68] = (float (*)[68])(smem + 4096);
    float (*p_lds)[256] = (float (*)[256])(smem + 4096 + 17408);

    const int lane = threadIdx.x & 63;
    const int w    = threadIdx.x >> 6;
    const int h = by, b = bz;
    const int q0 = bx * 16;
    const size_t base = (size_t)b * n * qstride;

    {
        int r = threadIdx.x >> 4, c4 = (threadIdx.x & 15) << 2;
        float4 v = *(const float4*)(qkv + base + (size_t)(q0 + r) * qstride + h * 64 + c4);
        q_lds[r][c4 + 0] = v.x; q_lds[r][c4 + 1] = v.y;
        q_lds[r][c4 + 2] = v.z; q_lds[r][c4 + 3] = v.w;
    }

    const int r0 = w * 4;
    const int sr = threadIdx.x >> 2;
    const int sq = threadIdx.x & 3;

    float s[4][NT];

    #pragma unroll
    for (int t = 0; t < NT; ++t) {
        const int j0 = t * 64;
        __syncthreads();
        {
            const float* src = qkv + base + (size_t)(j0 + sr) * qstride + 512 + h * 64;
            #pragma unroll
            for (int u = 0; u < 4; ++u) {
                int c = u * 4 + sq;
                float4 v = *(const float4*)(src + c * 4);
                *(float4*)&kv_lds[sr][c * 4] = v;
            }
        }
        __syncthreads();
        float c0 = 0.f, c1 = 0.f, c2 = 0.f, c3 = 0.f;
        #pragma unroll
        for (int d = 0; d < 64; d += 4) {
            const float4 kv = *(const float4*)&kv_lds[lane][d];
            const float4 qa = *(const float4*)&q_lds[r0 + 0][d];
            const float4 qb = *(const float4*)&q_lds[r0 + 1][d];
            const float4 qc = *(const float4*)&q_lds[r0 + 2][d];
            const float4 qd = *(const float4*)&q_lds[r0 + 3][d];
            c0 = fmaf(qa.x, kv.x, c0); c0 = fmaf(qa.y, kv.y, c0);
            c0 = fmaf(qa.z, kv.z, c0); c0 = fmaf(qa.w, kv.w, c0);
            c1 = fmaf(qb.x, kv.x, c1); c1 = fmaf(qb.y, kv.y, c1);
            c1 = fmaf(qb.z, kv.z, c1); c1 = fmaf(qb.w, kv.w, c1);
            c2 = fmaf(qc.x, kv.x, c2); c2 = fmaf(qc.y, kv.y, c2);
            c2 = fmaf(qc.z, kv.z, c2); c2 = fmaf(qc.w, kv.w, c2);
            c3 = fmaf(qd.x, kv.x, c3); c3 = fmaf(qd.y, kv.y, c3);
            c3 = fmaf(qd.z, kv.z, c3); c3 = fmaf(qd.w, kv.w, c3);
        }
        s[0][t] = c0 * 0.125f; s[1][t] = c1 * 0.125f;
        s[2][t] = c2 * 0.125f; s[3][t] = c3 * 0.125f;
    }

    double inv[4];
    #pragma unroll
    for (int qr = 0; qr < 4; ++qr) {
        float m = s[qr][0];
        #pragma unroll
        for (int t = 1; t < NT; ++t) m = fmaxf(m, s[qr][t]);
        #pragma unroll
        for (int off = 32; off; off >>= 1) m = fmaxf(m, __shfl_xor(m, off));
        double sum = 0.0;
        #pragma unroll
        for (int t = 0; t < NT; ++t) {
            float p = expf(s[qr][t] - m);
            p_lds[r0 + qr][t * 64 + lane] = p;
            sum += (double)p;
        }
        #pragma unroll
        for (int off = 32; off; off >>= 1) sum += __shfl_xor(sum, off);
        inv[qr] = 1.0 / sum;
    }

    float o0 = 0.f, o1 = 0.f, o2 = 0.f, o3 = 0.f;
    #pragma unroll
    for (int t = 0; t < NT; ++t) {
        const int j0 = t * 64;
        __syncthreads();
        {
            const float* src = qkv + base + (size_t)(j0 + sr) * qstride + 1024 + h * 64;
            #pragma unroll
            for (int u = 0; u < 4; ++u) {
                int c = u * 4 + sq;
                float4 v = *(const float4*)(src + c * 4);
                kv_lds[c * 4 + 0][sr] = v.x;
                kv_lds[c * 4 + 1][sr] = v.y;
                kv_lds[c * 4 + 2][sr] = v.z;
                kv_lds[c * 4 + 3][sr] = v.w;
            }
        }
        __syncthreads();
        #pragma unroll
        for (int jl = 0; jl < 64; jl += 4) {
            const float4 vv = *(const float4*)&kv_lds[lane][jl];
            const float4 pa = *(const float4*)&p_lds[r0 + 0][t * 64 + jl];
            const float4 pb = *(const float4*)&p_lds[r0 + 1][t * 64 + jl];
            const float4 pc = *(const float4*)&p_lds[r0 + 2][t * 64 + jl];
            const float4 pd = *(const float4*)&p_lds[r0 + 3][t * 64 + jl];
            o0 = fmaf(pa.x, vv.x, o0); o0 = fmaf(pa.y, vv.y, o0);
            o0 = fmaf(pa.z, vv.z, o0); o0 = fmaf(pa.w, vv.w, o0);
            o1 = fmaf(pb.x, vv.x, o1); o1 = fmaf(pb.y, vv.y, o1);
            o1 = fmaf(pb.z, vv.z, o1); o1 = fmaf(pb.w, vv.w, o1);
            o2 = fmaf(pc.x, vv.x, o2); o2 = fmaf(pc.y, vv.y, o2);
            o2 = fmaf(pc.z, vv.z, o2); o2 = fmaf(pc.w, vv.w, o2);
            o3 = fmaf(pd.x, vv.x, o3); o3 = fmaf(pd.y, vv.y, o3);
            o3 = fmaf(pd.z, vv.z, o3); o3 = fmaf(pd.w, vv.w, o3);
        }
    }
    const size_t obase = ((size_t)(b * n + q0 + r0)) * 512 + h * 64 + lane;
    const float r0v = (float)((double)o0 * inv[0]);
    const float r1v = (float)((double)o1 * inv[1]);
    const float r2v = (float)((double)o2 * inv[2]);
    const float r3v = (float)((double)o3 * inv[3]);
    out[obase + 0 * 512] = r0v;
    out[obase + 1 * 512] = r1v;
    out[obase + 2 * 512] = r2v;
    out[obase + 3 * 512] = r3v;
    if (outb) {
        outb[obase + 0 * 512] = f2bf(r0v);
        outb[obase + 1 * 512] = f2bf(r1v);
        outb[obase + 2 * 512] = f2bf(r2v);
        outb[obase + 3 * 512] = f2bf(r3v);
    }
}

template <int NT>
__global__ __launch_bounds__(256) void attn_v3(
    const float* __restrict__ qkv, float* __restrict__ out,
    unsigned short* __restrict__ outb, int n, int qstride)
{
    __shared__ __align__(16) char smem[37888];
    attn_dev<NT>(smem, qkv, out, outb, n, qstride, blockIdx.x, blockIdx.y, blockIdx.z);
}

// ---------------------------------------------------------------------------
// Edge scores device body: z[i,j] = sum_d relu(hi[i,d]+hj[j,d])*w2[d], f64.
// ---------------------------------------------------------------------------
__device__ __forceinline__ void scores_dev(
    char* smem, const float* __restrict__ hq, int stride, int off,
    const float* __restrict__ We2, const float* __restrict__ be2,
    float* __restrict__ S, int bx, int by, int bz)
{
    float (*Hi)[34] = (float (*)[34])smem;             // 17408 B
    float (*Hj)[34] = (float (*)[34])(smem + 17408);   // 17408 B
    const int b = bz;
    const int i0 = by * 32, j0 = bx * 32;
    const int tid = threadIdx.x;
    const int tx = tid & 15, ty = tid >> 4;

    const int si = tid >> 3;
    const int sd = (tid & 7) << 2;

    const float* hip = hq + (size_t)(b * 256 + i0 + si) * stride + off + sd;
    const float* hjp = hq + (size_t)(b * 256 + j0 + si) * stride + off + 512 + sd;

    double a00 = 0.0, a01 = 0.0, a10 = 0.0, a11 = 0.0;

    for (int k0 = 0; k0 < 512; k0 += 128) {
        __syncthreads();
        #pragma unroll
        for (int u = 0; u < 4; ++u) {
            const int dch = u * 32 + sd;
            float4 v = *(const float4*)(hip + k0 + u * 32);
            Hi[dch + 0][si] = v.x; Hi[dch + 1][si] = v.y;
            Hi[dch + 2][si] = v.z; Hi[dch + 3][si] = v.w;
            float4 w = *(const float4*)(hjp + k0 + u * 32);
            Hj[dch + 0][si] = w.x; Hj[dch + 1][si] = w.y;
            Hj[dch + 2][si] = w.z; Hj[dch + 3][si] = w.w;
        }
        __syncthreads();
        #pragma unroll 16
        for (int kk = 0; kk < 128; ++kk) {
            const double wv = (double)We2[k0 + kk];
            const float2 hi = *(const float2*)&Hi[kk][ty * 2];
            const float2 hj = *(const float2*)&Hj[kk][tx * 2];
            a00 += (double)fmaxf(hi.x + hj.x, 0.f) * wv;
            a01 += (double)fmaxf(hi.x + hj.y, 0.f) * wv;
            a10 += (double)fmaxf(hi.y + hj.x, 0.f) * wv;
            a11 += (double)fmaxf(hi.y + hj.y, 0.f) * wv;
        }
    }

    const double bb = (double)be2[0];
    const int gi0 = i0 + ty * 2, gj0 = j0 + tx * 2;
    double zz[2][2] = {{a00, a01}, {a10, a11}};
    #pragma unroll
    for (int ii = 0; ii < 2; ++ii)
        #pragma unroll
        for (int jj = 0; jj < 2; ++jj) {
            double z = zz[ii][jj] + bb;
            float sc_ = (float)(1.0 / (1.0 + exp(-z)));
            if (gi0 + ii == gj0 + jj) sc_ = 0.f;
            S[(size_t)(b * 256 + gi0 + ii) * 256 + gj0 + jj] = sc_;
        }
}

// ---------------------------------------------------------------------------
// Top-k(25) one-hot per row of 256, one WAVE per row (ties -> lower index).
// ---------------------------------------------------------------------------
__device__ __forceinline__ void topk_wave(
    const float* __restrict__ S, float* __restrict__ out, int row)
{
    const int lane = threadIdx.x & 63;
    float v[4]; int sel[4] = {0, 0, 0, 0};
    #pragma unroll
    for (int t = 0; t < 4; ++t) v[t] = S[(size_t)row * 256 + t * 64 + lane];
    for (int it = 0; it < 25; ++it) {
        float bv = v[0]; int bi = lane;
        #pragma unroll
        for (int t = 1; t < 4; ++t) {
            int idx = t * 64 + lane;
            if (v[t] > bv) { bv = v[t]; bi = idx; }
        }
        #pragma unroll
        for (int off = 32; off; off >>= 1) {
            float ov = __shfl_xor(bv, off);
            int   oi = __shfl_xor(bi, off);
            if (ov > bv || (ov == bv && oi < bi)) { bv = ov; bi = oi; }
        }
        if ((bi & 63) == lane) { int t = bi >> 6; sel[t] = 1; v[t] = -INFINITY; }
    }
    #pragma unroll
    for (int t = 0; t < 4; ++t)
        out[(size_t)row * 256 + t * 64 + lane] = (float)sel[t];
}

// ---------------------------------------------------------------------------
// Fused 3-way add + bias + relu + LayerNorm, one WAVE per row (4 rows/block).
// ---------------------------------------------------------------------------
__global__ __launch_bounds__(256) void ln3_k(
    const float* __restrict__ y, const float* __restrict__ bf,
    const float* __restrict__ g, const float* __restrict__ bta,
    float* __restrict__ out, unsigned short* __restrict__ outb)
{
    const int r = blockIdx.x * 4 + (threadIdx.x >> 6);
    const int lane = threadIdx.x & 63;
    const int b = r >> 8, i = r & 255;
    const float* y0 = y + (size_t)r * 512;
    const float* y1 = y + (size_t)(1024 + b * 128 + (i >> 1)) * 512;
    const float* y2 = y + (size_t)(1536 + b * 64 + (i >> 2)) * 512;
    double v[8];
    double sum = 0.0;
    #pragma unroll
    for (int t = 0; t < 8; ++t) {
        int d = t * 64 + lane;
        double s = (double)y0[d] + (double)y1[d] + (double)y2[d] + (double)bf[d];
        s = s > 0.0 ? s : 0.0;
        v[t] = s; sum += s;
    }
    #pragma unroll
    for (int off = 32; off; off >>= 1) sum += __shfl_xor(sum, off);
    const double mean = sum * (1.0 / 512.0);
    double ss = 0.0;
    #pragma unroll
    for (int t = 0; t < 8; ++t) { double d = v[t] - mean; ss += d * d; }
    #pragma unroll
    for (int off = 32; off; off >>= 1) ss += __shfl_xor(ss, off);
    const double rstd = 1.0 / sqrt(ss * (1.0 / 512.0) + 1e-5);
    #pragma unroll
    for (int t = 0; t < 8; ++t) {
        int d = t * 64 + lane;
        float f = (float)((v[t] - mean) * rstd * (double)g[d] + (double)bta[d]);
        out[(size_t)r * 512 + d] = f;
        outb[(size_t)r * 512 + d] = f2bf(f);
    }
}

// ---------------------------------------------------------------------------
// Packed dispatches (block-range union of mutually independent ops)
// ---------------------------------------------------------------------------
__global__ __launch_bounds__(256) void pack_qkv_cvt(
    const float* x, const float* Wqkv, const float* bqkv, float* qkvb,
    const float* Wsqkv, unsigned short* wqkvT,
    const float* Wso, unsigned short* wsoT)
{
    __shared__ __align__(16) char smem[9216];
    const int bid = blockIdx.x;
    if (bid < 384) {                       // qkv l0: grid (24,16)
        gemm_dev<64>(smem, x, Wqkv, bqkv, qkvb, 1024, 1536, 512, 0, 0,
                     bid % 24, bid / 24);
    } else if (bid < 576) {                // cvt Ws_qkv: grid (24,8)
        const int r = bid - 384;
        cvt_dev(smem, Wsqkv, wqkvT, 512, 1536, r % 24, r / 24);
    } else {                               // cvt Ws_o: grid (8,8)
        const int r = bid - 576;
        cvt_dev(smem, Wso, wsoT, 512, 512, r % 8, r / 8);
    }
}

// Wp1 (relu+pool) || fuse segment. nb_w = Wp1 blocks; fuse grid (8, Mf/64).
__global__ __launch_bounds__(256) void pack_wp1_fuse(
    const float* lvl, const float* Wp1, const float* bp1, float* poolb,
    const float* Wfseg, float* ydst, int Mw, int Mf, int nb_w)
{
    __shared__ __align__(16) char smem[8704];
    const int bid = blockIdx.x;
    if (bid < nb_w) {
        gemm_dev<32>(smem, lvl, Wp1, bp1, poolb, Mw, 256, 512, 3, 0,
                     bid % 4, bid / 4);
    } else {
        const int r = bid - nb_w;
        gemm_dev<64>(smem, lvl, Wfseg, nullptr, ydst, Mf, 512, 512, 0, 0,
                     r % 8, r / 8);
    }
}

__global__ __launch_bounds__(256) void pack_we1_mfma(
    const float* hier, const float* We1, const float* be1, float* hibjb,
    const unsigned short* hier_b, const unsigned short* wqkvT,
    const float* bs_qkv, float* qkvb)
{
    __shared__ __align__(16) char smem[8704];
    const int bid = blockIdx.x;
    if (bid < 256) {                       // We1: grid (16,16), wmode 2
        gemm_dev<64>(smem, hier, We1, be1, hibjb, 1024, 1024, 512, 0, 2,
                     bid % 16, bid / 16);
    } else {                               // mfma qkv: grid (24,8)
        const int r = bid - 256;
        mfma_dev(hier_b, wqkvT, bs_qkv, qkvb, 1024, 1536, 512, 1536,
                 r % 24, r / 24);
    }
}

__global__ __launch_bounds__(256) void pack_attnF_scores(
    const float* qkvb, float* attnb, unsigned short* attnb_b,
    const float* hibjb, const float* We2, const float* be2, float* scb)
{
    __shared__ __align__(16) char smem[37888];
    const int bid = blockIdx.x;
    if (bid < 512) {                       // final attn: grid (16,8,4)
        attn_dev<4>(smem, qkvb, attnb, attnb_b, 256, 1536,
                    bid % 16, (bid / 16) % 8, bid / 128);
    } else {                               // scores: grid (8,8,4)
        const int r = bid - 512;
        scores_dev(smem, hibjb, 1024, 0, We2, be2, scb,
                   r % 8, (r / 8) % 8, r / 64);
    }
}

__global__ __launch_bounds__(256) void pack_topk_mfma(
    const float* scb, float* out_sparse,
    const unsigned short* attnb_b, const unsigned short* wsoT,
    const float* bs_o, float* out_att)
{
    const int bid = blockIdx.x;
    if (bid < 256) {                       // topk: 4 rows/block (wave/row)
        topk_wave(scb, out_sparse, bid * 4 + (threadIdx.x >> 6));
    } else {                               // mfma o: grid (8,8)
        const int r = bid - 256;
        mfma_dev(attnb_b, wsoT, bs_o, out_att, 1024, 512, 512, 512,
                 r % 8, r / 8);
    }
}

// ---------------------------------------------------------------------------
extern "C" void kernel_launch(void* const* d_in, const int* in_sizes, int n_in,
                              void* d_out, int out_size, void* d_ws, size_t ws_size,
                              hipStream_t stream)
{
    const float* x      = (const float*)d_in[0];
    const float* Wqkv   = (const float*)d_in[2];
    const float* bqkv   = (const float*)d_in[3];
    const float* Wo     = (const float*)d_in[4];
    const float* bo     = (const float*)d_in[5];
    const float* Wp1    = (const float*)d_in[6];
    const float* bp1    = (const float*)d_in[7];
    const float* Wp2    = (const float*)d_in[8];
    const float* bp2    = (const float*)d_in[9];
    const float* Wfuse  = (const float*)d_in[10];
    const float* bfuse  = (const float*)d_in[11];
    const float* ln_g   = (const float*)d_in[12];
    const float* ln_b   = (const float*)d_in[13];
    const float* We1    = (const float*)d_in[14];
    const float* be1    = (const float*)d_in[15];
    const float* We2    = (const float*)d_in[16];
    const float* be2    = (const float*)d_in[17];
    const float* Ws_qkv = (const float*)d_in[18];
    const float* bs_qkv = (const float*)d_in[19];
    const float* Ws_o   = (const float*)d_in[20];
    const float* bs_o   = (const float*)d_in[21];

    float* out_att    = (float*)d_out;               // 4*256*512
    float* out_sparse = out_att + 4 * 256 * 512;     // 4*256*256

    // workspace layout (floats)
    float* ws    = (float*)d_ws;
    float* qkvb  = ws;                    // 1,572,864 (qkv activations only)
    float* attnb = qkvb + 1572864;        //   524,288
    float* lvls  = attnb + 524288;        //   917,504 (lvl0 | lvl1 | lvl2)
    float* poolb = lvls + 917504;         //   131,072
    float* curb  = poolb + 131072;        //   262,144
    float* hier  = curb + 262144;         //   524,288
    float* scb   = hier + 524288;         //   262,144
    float* hibjb = scb + 262144;          // 1,048,576 [1024][1024] (hi|hj)
    float* ybuf  = hibjb;                 // alias: fuse y (dead before We1)
    unsigned short* hier_b  = (unsigned short*)(hibjb + 1048576);  // 524,288
    unsigned short* attnb_b = hier_b + 524288;                     // 524,288
    unsigned short* wqkvT   = attnb_b + 524288;                    // 786,432
    unsigned short* wsoT    = wqkvT + 786432;                      // 262,144

    float* lvl0 = lvls;
    float* lvl1 = lvls + 1024 * 512;
    float* lvl2 = lvls + 1536 * 512;

    auto G64 = [&](const float* A, const float* W, const float* bias, float* C,
                   int M, int N, int K, int flags, int wmode) {
        gemm_v6<64><<<dim3(N / 64, M / 64), 256, 0, stream>>>(
            A, W, bias, C, M, N, K, flags, wmode);
    };
    auto G32 = [&](const float* A, const float* W, const float* bias, float* C,
                   int M, int N, int K, int flags, int wmode) {
        gemm_v6<32><<<dim3(N / 64, M / 32), 256, 0, stream>>>(
            A, W, bias, C, M, N, K, flags, wmode);
    };

    // D1: qkv l0  ||  both weight cvt->bf16^T
    pack_qkv_cvt<<<640, 256, 0, stream>>>(x, Wqkv, bqkv, qkvb,
                                          Ws_qkv, wqkvT, Ws_o, wsoT);
    // D2-D3
    attn_v3<4><<<dim3(16, 8, 4), 256, 0, stream>>>(qkvb, attnb, nullptr, 256, 1536);
    G32(attnb, Wo, bo, lvl0, 1024, 512, 512, 0, 0);
    // D4: Wp1 l0 (relu+pool) || fuse segment 0
    pack_wp1_fuse<<<256, 256, 0, stream>>>(lvl0, Wp1, bp1, poolb,
                                           Wfuse, ybuf, 1024, 1024, 128);
    // D5
    G32(poolb, Wp2, bp2, curb, 512, 512, 256, 0, 0);

    // ---- Level 1 ----
    G64(curb, Wqkv + 512 * 1536, bqkv + 1536, qkvb, 512, 1536, 512, 0, 0);
    attn_v3<2><<<dim3(8, 8, 4), 256, 0, stream>>>(qkvb, attnb, nullptr, 128, 1536);
    G32(attnb, Wo + 512 * 512, bo + 512, lvl1, 512, 512, 512, 0, 0);
    // D9: Wp1 l1 || fuse segment 1
    pack_wp1_fuse<<<128, 256, 0, stream>>>(lvl1, Wp1 + 512 * 256, bp1 + 256, poolb,
                                           Wfuse + 262144, ybuf + 1024 * 512,
                                           512, 512, 64);
    G32(poolb, Wp2 + 256 * 512, bp2 + 512, curb, 256, 512, 256, 0, 0);

    // ---- Level 2 ----
    G32(curb, Wqkv + 2 * 512 * 1536, bqkv + 2 * 1536, qkvb, 256, 1536, 512, 0, 0);
    attn_v3<1><<<dim3(4, 8, 4), 256, 0, stream>>>(qkvb, attnb, nullptr, 64, 1536);
    G32(attnb, Wo + 2 * 512 * 512, bo + 2 * 512, lvl2, 256, 512, 512, 0, 0);
    // D14: fuse segment 2
    G64(lvl2, Wfuse + 524288, nullptr, ybuf + 1536 * 512, 256, 512, 512, 0, 0);

    // D15: LN (emits f32 + bf16 hier)
    ln3_k<<<256, 256, 0, stream>>>(ybuf, bfuse, ln_g, ln_b, hier, hier_b);

    // D16: We1 (f32, score path) || mfma final-qkv (bf16)
    pack_we1_mfma<<<448, 256, 0, stream>>>(hier, We1, be1, hibjb,
                                           hier_b, wqkvT, bs_qkv, qkvb);
    // D17: final attn || scores
    pack_attnF_scores<<<768, 256, 0, stream>>>(qkvb, attnb, attnb_b,
                                               hibjb, We2, be2, scb);
    // D18: topk || mfma o-proj
    pack_topk_mfma<<<320, 256, 0, stream>>>(scb, out_sparse,
                                            attnb_b, wsoT, bs_o, out_att);
}

// Round 19
// 336.523 us; speedup vs baseline: 1.5407x; 1.0350x over previous
//
#include <hip/hip_runtime.h>
#include <math.h>

// Problem constants: B=4, N=256, D=512, H=8, HD=64, L=3, K_SPARSE=25, EPS=1e-5
// R18 = R17 (measured-good 348us) + two deltas:
//   1. scores_dev: f32 accumulation per 128-chunk, f64 across chunks
//      (numerics validated in R15/R16 passes: absmax unchanged, out1 exact)
//   2. pack_attnF_scores: __launch_bounds__(256,4) spill guard (<=128 VGPR),
//      blocking the R15/R16 pathological 256-VGPR regalloc schedule.

typedef __attribute__((ext_vector_type(8))) short bf16x8;
typedef __attribute__((ext_vector_type(4))) float f32x4;
typedef __attribute__((ext_vector_type(8))) unsigned short ushort8v;

__device__ __forceinline__ unsigned short f2bf(float x) {
    union { float f; unsigned int u; } c; c.f = x;
    unsigned int r = (c.u + 0x7fffu + ((c.u >> 16) & 1u)) >> 16;
    return (unsigned short)r;
}

// ---------------------------------------------------------------------------
// GEMM device body (f32): C[M,N] = act(A[M,K] @ W[K,N] + bias).
// TM=64: 4 rows x 4 cols/thread; TM=32: 2 rows x 4 cols.
// flags: 1 = relu, 2 = pool. wmode: 0 none; 2 = we1-split.
// ---------------------------------------------------------------------------
template <int TM>
__device__ __forceinline__ void gemm_dev(
    char* smem, const float* __restrict__ A, const float* __restrict__ W,
    const float* __restrict__ bias, float* __restrict__ C,
    int M, int N, int K, int flags, int wmode, int bx, int by)
{
    constexpr int RT = TM / 16;
    float (*As)[TM + 4] = (float (*)[TM + 4])smem;
    float (*Ws)[68] = (float (*)[68])(smem + 16 * (TM + 4) * sizeof(float));

    const int tid = threadIdx.x;
    const int tx = tid & 15, ty = tid >> 4;
    const int bm = by * TM, bn = bx * 64;

    const float* Wp = W;
    const float* bp = bias;
    int wn = N, wcol = bn;
    if (wmode == 2) {
        if (bn >= 512) Wp += 262144; else bp = nullptr;
        wn = 512; wcol = bn & 511;
    }

    constexpr int AV = (TM == 64) ? 4 : 2;
    const int ar = (TM == 64) ? (tid >> 2) : (tid >> 3);
    const int ac = (TM == 64) ? ((tid & 3) << 2) : ((tid & 7) << 1);
    const int wr = tid >> 4;
    const int wc = (tid & 15) << 2;

    const float* Aptr = A + (size_t)(bm + ar) * K + ac;
    const float* Wptr = Wp + (size_t)wr * wn + wcol + wc;

    float acc[RT][4] = {};
    float ra[AV], rw[4];

#define LOADREGS(k0_) do {                                                   \
        const float* ap_ = Aptr + (k0_);                                     \
        if constexpr (TM == 64) {                                            \
            float4 v_ = *(const float4*)ap_;                                 \
            ra[0]=v_.x; ra[1]=v_.y; ra[2]=v_.z; ra[3]=v_.w;                  \
        } else {                                                             \
            float2 v_ = *(const float2*)ap_; ra[0]=v_.x; ra[1]=v_.y;         \
        }                                                                    \
        float4 w_ = *(const float4*)(Wptr + (size_t)(k0_) * wn);             \
        rw[0]=w_.x; rw[1]=w_.y; rw[2]=w_.z; rw[3]=w_.w; } while (0)

    LOADREGS(0);

    for (int k0 = 0; k0 < K; k0 += 16) {
        if (k0) __syncthreads();
        #pragma unroll
        for (int u = 0; u < AV; ++u) As[ac + u][ar] = ra[u];
        #pragma unroll
        for (int u = 0; u < 4; ++u) Ws[wr][wc + u] = rw[u];
        __syncthreads();

        if (k0 + 16 < K) LOADREGS(k0 + 16);

        #pragma unroll
        for (int kk = 0; kk < 16; ++kk) {
            float a[RT];
            if constexpr (RT == 4) {
                float4 t = *(const float4*)&As[kk][ty * 4];
                a[0]=t.x; a[1]=t.y; a[2]=t.z; a[3]=t.w;
            } else {
                float2 t = *(const float2*)&As[kk][ty * 2];
                a[0]=t.x; a[1]=t.y;
            }
            float4 tw = *(const float4*)&Ws[kk][tx * 4];
            float w[4] = {tw.x, tw.y, tw.z, tw.w};
            #pragma unroll
            for (int i = 0; i < RT; ++i)
                #pragma unroll
                for (int j = 0; j < 4; ++j)
                    acc[i][j] = fmaf(a[i], w[j], acc[i][j]);
        }
    }
#undef LOADREGS

    #pragma unroll
    for (int j = 0; j < 4; ++j) {
        const int cn = bn + tx * 4 + j;
        const float bv = bp ? bp[wcol + tx * 4 + j] : 0.f;
        if (flags & 2) {
            #pragma unroll
            for (int pi = 0; pi < RT / 2; ++pi) {
                float f0 = acc[2 * pi][j] + bv;
                float f1 = acc[2 * pi + 1][j] + bv;
                if (flags & 1) { f0 = fmaxf(f0, 0.f); f1 = fmaxf(f1, 0.f); }
                int prow = ((bm + ty * RT) >> 1) + pi;
                C[(size_t)prow * N + cn] = (f0 + f1) * 0.5f;
            }
        } else {
            #pragma unroll
            for (int i = 0; i < RT; ++i) {
                float f = acc[i][j] + bv;
                if (flags & 1) f = fmaxf(f, 0.f);
                C[(size_t)(bm + ty * RT + i) * N + cn] = f;
            }
        }
    }
}

template <int TM>
__global__ __launch_bounds__(256) void gemm_v6(
    const float* __restrict__ A, const float* __restrict__ W,
    const float* __restrict__ bias, float* __restrict__ C,
    int M, int N, int K, int flags, int wmode)
{
    constexpr int SB = (TM == 64) ? 8704 : 6656;
    __shared__ __align__(16) char smem[SB];
    gemm_dev<TM>(smem, A, W, bias, C, M, N, K, flags, wmode, blockIdx.x, blockIdx.y);
}

// ---------------------------------------------------------------------------
// Transpose + f32->bf16 device body: Wt[N][K] = W[K][N]. 64x64 tiles.
// ---------------------------------------------------------------------------
__device__ __forceinline__ void cvt_dev(
    char* smem, const float* __restrict__ W, unsigned short* __restrict__ Wt,
    int K, int N, int bx, int by)
{
    unsigned short (*t)[72] = (unsigned short (*)[72])smem;
    const int n0 = bx * 64, k0 = by * 64;
    const int tid = threadIdx.x;
    const int rr = tid >> 4, c4 = (tid & 15) << 2;
    #pragma unroll
    for (int u = 0; u < 4; ++u) {
        const float4 v = *(const float4*)(W + (size_t)(k0 + rr + u * 16) * N + n0 + c4);
        t[c4 + 0][rr + u * 16] = f2bf(v.x);
        t[c4 + 1][rr + u * 16] = f2bf(v.y);
        t[c4 + 2][rr + u * 16] = f2bf(v.z);
        t[c4 + 3][rr + u * 16] = f2bf(v.w);
    }
    __syncthreads();
    const int orow = tid >> 2, oc = (tid & 3) << 4;
    unsigned short* dst = Wt + (size_t)(n0 + orow) * K + k0 + oc;
    *(ushort8v*)(dst + 0) = *(const ushort8v*)&t[orow][oc + 0];
    *(ushort8v*)(dst + 8) = *(const ushort8v*)&t[orow][oc + 8];
}

// ---------------------------------------------------------------------------
// MFMA bf16 GEMM device body (no LDS): C = A(bf16) @ Bt^T + bias.
// Block 256 = 4 waves; wave tile 32x64; block tile 128x64.
// ---------------------------------------------------------------------------
__device__ __forceinline__ void mfma_dev(
    const unsigned short* __restrict__ Ab, const unsigned short* __restrict__ Bt,
    const float* __restrict__ bias, float* __restrict__ C,
    int M, int N, int K, int ldc, int bx, int by)
{
    const int lane = threadIdx.x & 63;
    const int wv = threadIdx.x >> 6;
    const int bn = bx * 64;
    const int bm = by * 128 + wv * 32;
    const int l15 = lane & 15;
    const int kb = (lane >> 4) * 8;

    const unsigned short* a0p = Ab + (size_t)(bm + l15) * K + kb;
    const unsigned short* a1p = a0p + (size_t)16 * K;
    const unsigned short* bp0 = Bt + (size_t)(bn + l15) * K + kb;

    f32x4 acc[2][4];
    #pragma unroll
    for (int i = 0; i < 2; ++i)
        #pragma unroll
        for (int j = 0; j < 4; ++j)
            acc[i][j] = (f32x4){0.f, 0.f, 0.f, 0.f};

    for (int k0 = 0; k0 < K; k0 += 32) {
        const bf16x8 a0 = *(const bf16x8*)(a0p + k0);
        const bf16x8 a1 = *(const bf16x8*)(a1p + k0);
        #pragma unroll
        for (int nf = 0; nf < 4; ++nf) {
            const bf16x8 b = *(const bf16x8*)(bp0 + (size_t)nf * 16 * K + k0);
            acc[0][nf] = __builtin_amdgcn_mfma_f32_16x16x32_bf16(a0, b, acc[0][nf], 0, 0, 0);
            acc[1][nf] = __builtin_amdgcn_mfma_f32_16x16x32_bf16(a1, b, acc[1][nf], 0, 0, 0);
        }
    }

    const int r0 = (lane >> 4) * 4;
    #pragma unroll
    for (int mf = 0; mf < 2; ++mf)
        #pragma unroll
        for (int nf = 0; nf < 4; ++nf) {
            const int col = bn + nf * 16 + l15;
            const float bv = bias ? bias[col] : 0.f;
            #pragma unroll
            for (int r = 0; r < 4; ++r) {
                const int row = bm + mf * 16 + r0 + r;
                C[(size_t)row * ldc + col] = acc[mf][nf][r] + bv;
            }
        }
}

// ---------------------------------------------------------------------------
// Fused MHA device body. Block = (16 q-rows, h, b), 4 waves; wave owns 4
// q-rows. NT = n/64. Q staged in LDS; b128 LDS reads; V staged transposed.
// Optional bf16 shadow output (outb != nullptr).
// LDS: q[16][64] 4096 + kv[64][68] 17408 + p[16][256] 16384 = 37888 B.
// ---------------------------------------------------------------------------
template <int NT>
__device__ __forceinline__ void attn_dev(
    char* smem, const float* __restrict__ qkv, float* __restrict__ out,
    unsigned short* __restrict__ outb, int n, int qstride,
    int bx, int by, int bz)
{
    float (*q_lds)[64]  = (float (*)[64])smem;
    float (*kv_lds)[68] = (float (*)[68])(smem + 4096);
    float (*p_lds)[256] = (float (*)[256])(smem + 4096 + 17408);

    const int lane = threadIdx.x & 63;
    const int w    = threadIdx.x >> 6;
    const int h = by, b = bz;
    const int q0 = bx * 16;
    const size_t base = (size_t)b * n * qstride;

    {
        int r = threadIdx.x >> 4, c4 = (threadIdx.x & 15) << 2;
        float4 v = *(const float4*)(qkv + base + (size_t)(q0 + r) * qstride + h * 64 + c4);
        q_lds[r][c4 + 0] = v.x; q_lds[r][c4 + 1] = v.y;
        q_lds[r][c4 + 2] = v.z; q_lds[r][c4 + 3] = v.w;
    }

    const int r0 = w * 4;
    const int sr = threadIdx.x >> 2;
    const int sq = threadIdx.x & 3;

    float s[4][NT];

    #pragma unroll
    for (int t = 0; t < NT; ++t) {
        const int j0 = t * 64;
        __syncthreads();
        {
            const float* src = qkv + base + (size_t)(j0 + sr) * qstride + 512 + h * 64;
            #pragma unroll
            for (int u = 0; u < 4; ++u) {
                int c = u * 4 + sq;
                float4 v = *(const float4*)(src + c * 4);
                *(float4*)&kv_lds[sr][c * 4] = v;
            }
        }
        __syncthreads();
        float c0 = 0.f, c1 = 0.f, c2 = 0.f, c3 = 0.f;
        #pragma unroll
        for (int d = 0; d < 64; d += 4) {
            const float4 kv = *(const float4*)&kv_lds[lane][d];
            const float4 qa = *(const float4*)&q_lds[r0 + 0][d];
            const float4 qb = *(const float4*)&q_lds[r0 + 1][d];
            const float4 qc = *(const float4*)&q_lds[r0 + 2][d];
            const float4 qd = *(const float4*)&q_lds[r0 + 3][d];
            c0 = fmaf(qa.x, kv.x, c0); c0 = fmaf(qa.y, kv.y, c0);
            c0 = fmaf(qa.z, kv.z, c0); c0 = fmaf(qa.w, kv.w, c0);
            c1 = fmaf(qb.x, kv.x, c1); c1 = fmaf(qb.y, kv.y, c1);
            c1 = fmaf(qb.z, kv.z, c1); c1 = fmaf(qb.w, kv.w, c1);
            c2 = fmaf(qc.x, kv.x, c2); c2 = fmaf(qc.y, kv.y, c2);
            c2 = fmaf(qc.z, kv.z, c2); c2 = fmaf(qc.w, kv.w, c2);
            c3 = fmaf(qd.x, kv.x, c3); c3 = fmaf(qd.y, kv.y, c3);
            c3 = fmaf(qd.z, kv.z, c3); c3 = fmaf(qd.w, kv.w, c3);
        }
        s[0][t] = c0 * 0.125f; s[1][t] = c1 * 0.125f;
        s[2][t] = c2 * 0.125f; s[3][t] = c3 * 0.125f;
    }

    double inv[4];
    #pragma unroll
    for (int qr = 0; qr < 4; ++qr) {
        float m = s[qr][0];
        #pragma unroll
        for (int t = 1; t < NT; ++t) m = fmaxf(m, s[qr][t]);
        #pragma unroll
        for (int off = 32; off; off >>= 1) m = fmaxf(m, __shfl_xor(m, off));
        double sum = 0.0;
        #pragma unroll
        for (int t = 0; t < NT; ++t) {
            float p = expf(s[qr][t] - m);
            p_lds[r0 + qr][t * 64 + lane] = p;
            sum += (double)p;
        }
        #pragma unroll
        for (int off = 32; off; off >>= 1) sum += __shfl_xor(sum, off);
        inv[qr] = 1.0 / sum;
    }

    float o0 = 0.f, o1 = 0.f, o2 = 0.f, o3 = 0.f;
    #pragma unroll
    for (int t = 0; t < NT; ++t) {
        const int j0 = t * 64;
        __syncthreads();
        {
            const float* src = qkv + base + (size_t)(j0 + sr) * qstride + 1024 + h * 64;
            #pragma unroll
            for (int u = 0; u < 4; ++u) {
                int c = u * 4 + sq;
                float4 v = *(const float4*)(src + c * 4);
                kv_lds[c * 4 + 0][sr] = v.x;
                kv_lds[c * 4 + 1][sr] = v.y;
                kv_lds[c * 4 + 2][sr] = v.z;
                kv_lds[c * 4 + 3][sr] = v.w;
            }
        }
        __syncthreads();
        #pragma unroll
        for (int jl = 0; jl < 64; jl += 4) {
            const float4 vv = *(const float4*)&kv_lds[lane][jl];
            const float4 pa = *(const float4*)&p_lds[r0 + 0][t * 64 + jl];
            const float4 pb = *(const float4*)&p_lds[r0 + 1][t * 64 + jl];
            const float4 pc = *(const float4*)&p_lds[r0 + 2][t * 64 + jl];
            const float4 pd = *(const float4*)&p_lds[r0 + 3][t * 64 + jl];
            o0 = fmaf(pa.x, vv.x, o0); o0 = fmaf(pa.y, vv.y, o0);
            o0 = fmaf(pa.z, vv.z, o0); o0 = fmaf(pa.w, vv.w, o0);
            o1 = fmaf(pb.x, vv.x, o1); o1 = fmaf(pb.y, vv.y, o1);
            o1 = fmaf(pb.z, vv.z, o1); o1 = fmaf(pb.w, vv.w, o1);
            o2 = fmaf(pc.x, vv.x, o2); o2 = fmaf(pc.y, vv.y, o2);
            o2 = fmaf(pc.z, vv.z, o2); o2 = fmaf(pc.w, vv.w, o2);
            o3 = fmaf(pd.x, vv.x, o3); o3 = fmaf(pd.y, vv.y, o3);
            o3 = fmaf(pd.z, vv.z, o3); o3 = fmaf(pd.w, vv.w, o3);
        }
    }
    const size_t obase = ((size_t)(b * n + q0 + r0)) * 512 + h * 64 + lane;
    const float r0v = (float)((double)o0 * inv[0]);
    const float r1v = (float)((double)o1 * inv[1]);
    const float r2v = (float)((double)o2 * inv[2]);
    const float r3v = (float)((double)o3 * inv[3]);
    out[obase + 0 * 512] = r0v;
    out[obase + 1 * 512] = r1v;
    out[obase + 2 * 512] = r2v;
    out[obase + 3 * 512] = r3v;
    if (outb) {
        outb[obase + 0 * 512] = f2bf(r0v);
        outb[obase + 1 * 512] = f2bf(r1v);
        outb[obase + 2 * 512] = f2bf(r2v);
        outb[obase + 3 * 512] = f2bf(r3v);
    }
}

template <int NT>
__global__ __launch_bounds__(256) void attn_v3(
    const float* __restrict__ qkv, float* __restrict__ out,
    unsigned short* __restrict__ outb, int n, int qstride)
{
    __shared__ __align__(16) char smem[37888];
    attn_dev<NT>(smem, qkv, out, outb, n, qstride, blockIdx.x, blockIdx.y, blockIdx.z);
}

// ---------------------------------------------------------------------------
// Edge scores device body: z[i,j] = sum_d relu(hi[i,d]+hj[j,d])*w2[d].
// f32 accumulation within each 128-deep chunk, f64 across chunks
// (validated: R15/R16 passed with identical absmax, output 1 exact).
// We2 scalar f32 loads (loop-counter index -> SGPR path).
// ---------------------------------------------------------------------------
__device__ __forceinline__ void scores_dev(
    char* smem, const float* __restrict__ hq, int stride, int off,
    const float* __restrict__ We2, const float* __restrict__ be2,
    float* __restrict__ S, int bx, int by, int bz)
{
    float (*Hi)[34] = (float (*)[34])smem;             // 17408 B
    float (*Hj)[34] = (float (*)[34])(smem + 17408);   // 17408 B
    const int b = bz;
    const int i0 = by * 32, j0 = bx * 32;
    const int tid = threadIdx.x;
    const int tx = tid & 15, ty = tid >> 4;

    const int si = tid >> 3;
    const int sd = (tid & 7) << 2;

    const float* hip = hq + (size_t)(b * 256 + i0 + si) * stride + off + sd;
    const float* hjp = hq + (size_t)(b * 256 + j0 + si) * stride + off + 512 + sd;

    double a00 = 0.0, a01 = 0.0, a10 = 0.0, a11 = 0.0;

    for (int k0 = 0; k0 < 512; k0 += 128) {
        __syncthreads();
        #pragma unroll
        for (int u = 0; u < 4; ++u) {
            const int dch = u * 32 + sd;
            float4 v = *(const float4*)(hip + k0 + u * 32);
            Hi[dch + 0][si] = v.x; Hi[dch + 1][si] = v.y;
            Hi[dch + 2][si] = v.z; Hi[dch + 3][si] = v.w;
            float4 w = *(const float4*)(hjp + k0 + u * 32);
            Hj[dch + 0][si] = w.x; Hj[dch + 1][si] = w.y;
            Hj[dch + 2][si] = w.z; Hj[dch + 3][si] = w.w;
        }
        __syncthreads();
        float c00 = 0.f, c01 = 0.f, c10 = 0.f, c11 = 0.f;
        #pragma unroll 16
        for (int kk = 0; kk < 128; ++kk) {
            const float wv = We2[k0 + kk];   // wave-uniform -> s_load
            const float2 hi = *(const float2*)&Hi[kk][ty * 2];
            const float2 hj = *(const float2*)&Hj[kk][tx * 2];
            c00 = fmaf(fmaxf(hi.x + hj.x, 0.f), wv, c00);
            c01 = fmaf(fmaxf(hi.x + hj.y, 0.f), wv, c01);
            c10 = fmaf(fmaxf(hi.y + hj.x, 0.f), wv, c10);
            c11 = fmaf(fmaxf(hi.y + hj.y, 0.f), wv, c11);
        }
        a00 += (double)c00; a01 += (double)c01;
        a10 += (double)c10; a11 += (double)c11;
    }

    const double bb = (double)be2[0];
    const int gi0 = i0 + ty * 2, gj0 = j0 + tx * 2;
    double zz[2][2] = {{a00, a01}, {a10, a11}};
    #pragma unroll
    for (int ii = 0; ii < 2; ++ii)
        #pragma unroll
        for (int jj = 0; jj < 2; ++jj) {
            double z = zz[ii][jj] + bb;
            float sc_ = (float)(1.0 / (1.0 + exp(-z)));
            if (gi0 + ii == gj0 + jj) sc_ = 0.f;
            S[(size_t)(b * 256 + gi0 + ii) * 256 + gj0 + jj] = sc_;
        }
}

// ---------------------------------------------------------------------------
// Top-k(25) one-hot per row of 256, one WAVE per row (ties -> lower index).
// ---------------------------------------------------------------------------
__device__ __forceinline__ void topk_wave(
    const float* __restrict__ S, float* __restrict__ out, int row)
{
    const int lane = threadIdx.x & 63;
    float v[4]; int sel[4] = {0, 0, 0, 0};
    #pragma unroll
    for (int t = 0; t < 4; ++t) v[t] = S[(size_t)row * 256 + t * 64 + lane];
    for (int it = 0; it < 25; ++it) {
        float bv = v[0]; int bi = lane;
        #pragma unroll
        for (int t = 1; t < 4; ++t) {
            int idx = t * 64 + lane;
            if (v[t] > bv) { bv = v[t]; bi = idx; }
        }
        #pragma unroll
        for (int off = 32; off; off >>= 1) {
            float ov = __shfl_xor(bv, off);
            int   oi = __shfl_xor(bi, off);
            if (ov > bv || (ov == bv && oi < bi)) { bv = ov; bi = oi; }
        }
        if ((bi & 63) == lane) { int t = bi >> 6; sel[t] = 1; v[t] = -INFINITY; }
    }
    #pragma unroll
    for (int t = 0; t < 4; ++t)
        out[(size_t)row * 256 + t * 64 + lane] = (float)sel[t];
}

// ---------------------------------------------------------------------------
// Fused 3-way add + bias + relu + LayerNorm, one WAVE per row (4 rows/block).
// ---------------------------------------------------------------------------
__global__ __launch_bounds__(256) void ln3_k(
    const float* __restrict__ y, const float* __restrict__ bf,
    const float* __restrict__ g, const float* __restrict__ bta,
    float* __restrict__ out, unsigned short* __restrict__ outb)
{
    const int r = blockIdx.x * 4 + (threadIdx.x >> 6);
    const int lane = threadIdx.x & 63;
    const int b = r >> 8, i = r & 255;
    const float* y0 = y + (size_t)r * 512;
    const float* y1 = y + (size_t)(1024 + b * 128 + (i >> 1)) * 512;
    const float* y2 = y + (size_t)(1536 + b * 64 + (i >> 2)) * 512;
    double v[8];
    double sum = 0.0;
    #pragma unroll
    for (int t = 0; t < 8; ++t) {
        int d = t * 64 + lane;
        double s = (double)y0[d] + (double)y1[d] + (double)y2[d] + (double)bf[d];
        s = s > 0.0 ? s : 0.0;
        v[t] = s; sum += s;
    }
    #pragma unroll
    for (int off = 32; off; off >>= 1) sum += __shfl_xor(sum, off);
    const double mean = sum * (1.0 / 512.0);
    double ss = 0.0;
    #pragma unroll
    for (int t = 0; t < 8; ++t) { double d = v[t] - mean; ss += d * d; }
    #pragma unroll
    for (int off = 32; off; off >>= 1) ss += __shfl_xor(ss, off);
    const double rstd = 1.0 / sqrt(ss * (1.0 / 512.0) + 1e-5);
    #pragma unroll
    for (int t = 0; t < 8; ++t) {
        int d = t * 64 + lane;
        float f = (float)((v[t] - mean) * rstd * (double)g[d] + (double)bta[d]);
        out[(size_t)r * 512 + d] = f;
        outb[(size_t)r * 512 + d] = f2bf(f);
    }
}

// ---------------------------------------------------------------------------
// Packed dispatches (block-range union of mutually independent ops)
// ---------------------------------------------------------------------------
__global__ __launch_bounds__(256) void pack_qkv_cvt(
    const float* x, const float* Wqkv, const float* bqkv, float* qkvb,
    const float* Wsqkv, unsigned short* wqkvT,
    const float* Wso, unsigned short* wsoT)
{
    __shared__ __align__(16) char smem[9216];
    const int bid = blockIdx.x;
    if (bid < 384) {                       // qkv l0: grid (24,16)
        gemm_dev<64>(smem, x, Wqkv, bqkv, qkvb, 1024, 1536, 512, 0, 0,
                     bid % 24, bid / 24);
    } else if (bid < 576) {                // cvt Ws_qkv: grid (24,8)
        const int r = bid - 384;
        cvt_dev(smem, Wsqkv, wqkvT, 512, 1536, r % 24, r / 24);
    } else {                               // cvt Ws_o: grid (8,8)
        const int r = bid - 576;
        cvt_dev(smem, Wso, wsoT, 512, 512, r % 8, r / 8);
    }
}

// Wp1 (relu+pool) || fuse segment. nb_w = Wp1 blocks; fuse grid (8, Mf/64).
__global__ __launch_bounds__(256) void pack_wp1_fuse(
    const float* lvl, const float* Wp1, const float* bp1, float* poolb,
    const float* Wfseg, float* ydst, int Mw, int Mf, int nb_w)
{
    __shared__ __align__(16) char smem[8704];
    const int bid = blockIdx.x;
    if (bid < nb_w) {
        gemm_dev<32>(smem, lvl, Wp1, bp1, poolb, Mw, 256, 512, 3, 0,
                     bid % 4, bid / 4);
    } else {
        const int r = bid - nb_w;
        gemm_dev<64>(smem, lvl, Wfseg, nullptr, ydst, Mf, 512, 512, 0, 0,
                     r % 8, r / 8);
    }
}

__global__ __launch_bounds__(256) void pack_we1_mfma(
    const float* hier, const float* We1, const float* be1, float* hibjb,
    const unsigned short* hier_b, const unsigned short* wqkvT,
    const float* bs_qkv, float* qkvb)
{
    __shared__ __align__(16) char smem[8704];
    const int bid = blockIdx.x;
    if (bid < 256) {                       // We1: grid (16,16), wmode 2
        gemm_dev<64>(smem, hier, We1, be1, hibjb, 1024, 1024, 512, 0, 2,
                     bid % 16, bid / 16);
    } else {                               // mfma qkv: grid (24,8)
        const int r = bid - 256;
        mfma_dev(hier_b, wqkvT, bs_qkv, qkvb, 1024, 1536, 512, 1536,
                 r % 24, r / 24);
    }
}

__global__ __launch_bounds__(256, 4) void pack_attnF_scores(
    const float* qkvb, float* attnb, unsigned short* attnb_b,
    const float* hibjb, const float* We2, const float* be2, float* scb)
{
    __shared__ __align__(16) char smem[37888];
    const int bid = blockIdx.x;
    if (bid < 512) {                       // final attn: grid (16,8,4)
        attn_dev<4>(smem, qkvb, attnb, attnb_b, 256, 1536,
                    bid % 16, (bid / 16) % 8, bid / 128);
    } else {                               // scores: grid (8,8,4)
        const int r = bid - 512;
        scores_dev(smem, hibjb, 1024, 0, We2, be2, scb,
                   r % 8, (r / 8) % 8, r / 64);
    }
}

__global__ __launch_bounds__(256) void pack_topk_mfma(
    const float* scb, float* out_sparse,
    const unsigned short* attnb_b, const unsigned short* wsoT,
    const float* bs_o, float* out_att)
{
    const int bid = blockIdx.x;
    if (bid < 256) {                       // topk: 4 rows/block (wave/row)
        topk_wave(scb, out_sparse, bid * 4 + (threadIdx.x >> 6));
    } else {                               // mfma o: grid (8,8)
        const int r = bid - 256;
        mfma_dev(attnb_b, wsoT, bs_o, out_att, 1024, 512, 512, 512,
                 r % 8, r / 8);
    }
}

// ---------------------------------------------------------------------------
extern "C" void kernel_launch(void* const* d_in, const int* in_sizes, int n_in,
                              void* d_out, int out_size, void* d_ws, size_t ws_size,
                              hipStream_t stream)
{
    const float* x      = (const float*)d_in[0];
    const float* Wqkv   = (const float*)d_in[2];
    const float* bqkv   = (const float*)d_in[3];
    const float* Wo     = (const float*)d_in[4];
    const float* bo     = (const float*)d_in[5];
    const float* Wp1    = (const float*)d_in[6];
    const float* bp1    = (const float*)d_in[7];
    const float* Wp2    = (const float*)d_in[8];
    const float* bp2    = (const float*)d_in[9];
    const float* Wfuse  = (const float*)d_in[10];
    const float* bfuse  = (const float*)d_in[11];
    const float* ln_g   = (const float*)d_in[12];
    const float* ln_b   = (const float*)d_in[13];
    const float* We1    = (const float*)d_in[14];
    const float* be1    = (const float*)d_in[15];
    const float* We2    = (const float*)d_in[16];
    const float* be2    = (const float*)d_in[17];
    const float* Ws_qkv = (const float*)d_in[18];
    const float* bs_qkv = (const float*)d_in[19];
    const float* Ws_o   = (const float*)d_in[20];
    const float* bs_o   = (const float*)d_in[21];

    float* out_att    = (float*)d_out;               // 4*256*512
    float* out_sparse = out_att + 4 * 256 * 512;     // 4*256*256

    // workspace layout (floats)
    float* ws    = (float*)d_ws;
    float* qkvb  = ws;                    // 1,572,864 (qkv activations only)
    float* attnb = qkvb + 1572864;        //   524,288
    float* lvls  = attnb + 524288;        //   917,504 (lvl0 | lvl1 | lvl2)
    float* poolb = lvls + 917504;         //   131,072
    float* curb  = poolb + 131072;        //   262,144
    float* hier  = curb + 262144;         //   524,288
    float* scb   = hier + 524288;         //   262,144
    float* hibjb = scb + 262144;          // 1,048,576 [1024][1024] (hi|hj)
    float* ybuf  = hibjb;                 // alias: fuse y (dead before We1)
    unsigned short* hier_b  = (unsigned short*)(hibjb + 1048576);  // 524,288
    unsigned short* attnb_b = hier_b + 524288;                     // 524,288
    unsigned short* wqkvT   = attnb_b + 524288;                    // 786,432
    unsigned short* wsoT    = wqkvT + 786432;                      // 262,144

    float* lvl0 = lvls;
    float* lvl1 = lvls + 1024 * 512;
    float* lvl2 = lvls + 1536 * 512;

    auto G64 = [&](const float* A, const float* W, const float* bias, float* C,
                   int M, int N, int K, int flags, int wmode) {
        gemm_v6<64><<<dim3(N / 64, M / 64), 256, 0, stream>>>(
            A, W, bias, C, M, N, K, flags, wmode);
    };
    auto G32 = [&](const float* A, const float* W, const float* bias, float* C,
                   int M, int N, int K, int flags, int wmode) {
        gemm_v6<32><<<dim3(N / 64, M / 32), 256, 0, stream>>>(
            A, W, bias, C, M, N, K, flags, wmode);
    };

    // D1: qkv l0  ||  both weight cvt->bf16^T
    pack_qkv_cvt<<<640, 256, 0, stream>>>(x, Wqkv, bqkv, qkvb,
                                          Ws_qkv, wqkvT, Ws_o, wsoT);
    // D2-D3
    attn_v3<4><<<dim3(16, 8, 4), 256, 0, stream>>>(qkvb, attnb, nullptr, 256, 1536);
    G32(attnb, Wo, bo, lvl0, 1024, 512, 512, 0, 0);
    // D4: Wp1 l0 (relu+pool) || fuse segment 0
    pack_wp1_fuse<<<256, 256, 0, stream>>>(lvl0, Wp1, bp1, poolb,
                                           Wfuse, ybuf, 1024, 1024, 128);
    // D5
    G32(poolb, Wp2, bp2, curb, 512, 512, 256, 0, 0);

    // ---- Level 1 ----
    G64(curb, Wqkv + 512 * 1536, bqkv + 1536, qkvb, 512, 1536, 512, 0, 0);
    attn_v3<2><<<dim3(8, 8, 4), 256, 0, stream>>>(qkvb, attnb, nullptr, 128, 1536);
    G32(attnb, Wo + 512 * 512, bo + 512, lvl1, 512, 512, 512, 0, 0);
    // D9: Wp1 l1 || fuse segment 1
    pack_wp1_fuse<<<128, 256, 0, stream>>>(lvl1, Wp1 + 512 * 256, bp1 + 256, poolb,
                                           Wfuse + 262144, ybuf + 1024 * 512,
                                           512, 512, 64);
    G32(poolb, Wp2 + 256 * 512, bp2 + 512, curb, 256, 512, 256, 0, 0);

    // ---- Level 2 ----
    G32(curb, Wqkv + 2 * 512 * 1536, bqkv + 2 * 1536, qkvb, 256, 1536, 512, 0, 0);
    attn_v3<1><<<dim3(4, 8, 4), 256, 0, stream>>>(qkvb, attnb, nullptr, 64, 1536);
    G32(attnb, Wo + 2 * 512 * 512, bo + 2 * 512, lvl2, 256, 512, 512, 0, 0);
    // D14: fuse segment 2
    G64(lvl2, Wfuse + 524288, nullptr, ybuf + 1536 * 512, 256, 512, 512, 0, 0);

    // D15: LN (emits f32 + bf16 hier)
    ln3_k<<<256, 256, 0, stream>>>(ybuf, bfuse, ln_g, ln_b, hier, hier_b);

    // D16: We1 (f32, score path) || mfma final-qkv (bf16)
    pack_we1_mfma<<<448, 256, 0, stream>>>(hier, We1, be1, hibjb,
                                           hier_b, wqkvT, bs_qkv, qkvb);
    // D17: final attn || scores
    pack_attnF_scores<<<768, 256, 0, stream>>>(qkvb, attnb, attnb_b,
                                               hibjb, We2, be2, scb);
    // D18: topk || mfma o-proj
    pack_topk_mfma<<<320, 256, 0, stream>>>(scb, out_sparse,
                                            attnb_b, wsoT, bs_o, out_att);
}